// Round 1
// baseline (11490.165 us; speedup 1.0000x reference)
//
#include <hip/hip_runtime.h>
#include <math.h>

// ---------------------------------------------------------------------------
// LearnableWeightedRGCN — fp32 correctness-first pipeline.
// N=50000 nodes, D=256, R=4 relations, E=800000 edges/relation.
//
// Pipeline:
//   1. x = gelu(LN1(node_emb @ pre_W + pre_b))          [gemm_fused<0>]
//   2. agg[r] = segment_sum(vals[r] * x[cols[r]], rows[r])   [atomics]
//   3. w~[r] = rel_W[r] @ attn_vec  (tiny)
//   4. attn[n][r] = softmax_r( mask ? agg[r][n]·w~[r] : -1e30 ) * mask
//   5. final = LN2(gelu( [attn-scaled agg | x] @ [rel_W ; self_W] + bias + self_b ))
//   6. x_all out = node_emb (D2D copy)
// ---------------------------------------------------------------------------

__device__ __forceinline__ float gelu_exact(float v) {
    return 0.5f * v * (1.0f + erff(v * 0.70710678118654752f));
}

// ---------------------------------------------------------------------------
// Row-block GEMM: each block computes 64 full rows (256 cols). 256 threads,
// 8x8 micro-tile per thread. Thread (tr,tc) owns rows brow+tr*8+i and split
// columns {tc*4+j, 128+tc*4+j} (conflict-free contiguous-float4 LDS reads).
// MODE 0 (pre):  C = gelu(LN(A@B0 + bias0; lng,lnb)),        K=256
// MODE 1 (mega): A'[m][k] = k<1024 ? attn[m][k>>8]*agg[(k>>8)][m][k&255]
//                                  : A[m][k-1024]   (A = x)
//                B'       = k<1024 ? B0(rel_W flat [1024][256]) : B1(self_W)
//                C = LN(gelu(A'@B' + bias0 + bias1); lng,lnb), K=1280
// ---------------------------------------------------------------------------
template<int MODE>
__global__ __launch_bounds__(256)
void gemm_fused(const float* __restrict__ A, const float* __restrict__ agg,
                const float* __restrict__ attn, const float* __restrict__ B0,
                const float* __restrict__ B1, const float* __restrict__ bias0,
                const float* __restrict__ bias1, const float* __restrict__ lng,
                const float* __restrict__ lnb, float* __restrict__ C, int M)
{
    constexpr int K = (MODE == 0) ? 256 : 1280;
    __shared__ float As[16][68];    // padded: k-major, [k][m]
    __shared__ float Bs[16][256];   // [k][n]
    const int tid  = threadIdx.x;
    const int tr   = tid >> 5;          // 0..7
    const int tc   = tid & 31;          // 0..31
    const int brow = blockIdx.x * 64;
    const int lm   = tid >> 2;          // 0..63 (A staging row)
    const int lk   = (tid & 3) << 2;    // 0,4,8,12 (A staging k)
    const int gm   = brow + lm;

    float acc[8][8];
#pragma unroll
    for (int i = 0; i < 8; ++i) {
#pragma unroll
        for (int j = 0; j < 8; ++j) acc[i][j] = 0.0f;
    }

    for (int kt = 0; kt < K; kt += 16) {
        // ---- stage A tile (64 rows x 16 k) ----
        float4 av = make_float4(0.f, 0.f, 0.f, 0.f);
        if (gm < M) {
            const float* src;
            float scale = 1.0f;
            if (MODE == 0) {
                src = A + (size_t)gm * 256 + kt + lk;
            } else {
                if (kt < 1024) {
                    const int r = kt >> 8;
                    src = agg + (((size_t)r * M + gm) << 8) + (kt & 255) + lk;
                    scale = attn[(size_t)gm * 4 + r];
                } else {
                    src = A + (size_t)gm * 256 + (kt - 1024) + lk;
                }
            }
            av = *reinterpret_cast<const float4*>(src);
            av.x *= scale; av.y *= scale; av.z *= scale; av.w *= scale;
        }
        As[lk + 0][lm] = av.x;
        As[lk + 1][lm] = av.y;
        As[lk + 2][lm] = av.z;
        As[lk + 3][lm] = av.w;

        // ---- stage B tile (16 k x 256 n) ----
        {
            const float* Bsrc = (MODE == 0 || kt < 1024)
                                ? (B0 + (size_t)kt * 256)
                                : (B1 + (size_t)(kt - 1024) * 256);
#pragma unroll
            for (int t = 0; t < 4; ++t) {
                const int f  = tid + t * 256;
                const int k  = f >> 6;
                const int n4 = (f & 63) << 2;
                *reinterpret_cast<float4*>(&Bs[k][n4]) =
                    *reinterpret_cast<const float4*>(Bsrc + (size_t)k * 256 + n4);
            }
        }
        __syncthreads();

#pragma unroll
        for (int k = 0; k < 16; ++k) {
            float a[8], b[8];
            *reinterpret_cast<float4*>(&a[0]) = *reinterpret_cast<const float4*>(&As[k][tr * 8]);
            *reinterpret_cast<float4*>(&a[4]) = *reinterpret_cast<const float4*>(&As[k][tr * 8 + 4]);
            *reinterpret_cast<float4*>(&b[0]) = *reinterpret_cast<const float4*>(&Bs[k][tc * 4]);
            *reinterpret_cast<float4*>(&b[4]) = *reinterpret_cast<const float4*>(&Bs[k][128 + tc * 4]);
#pragma unroll
            for (int i = 0; i < 8; ++i) {
#pragma unroll
                for (int j = 0; j < 8; ++j) acc[i][j] = fmaf(a[i], b[j], acc[i][j]);
            }
        }
        __syncthreads();
    }

    // ---- epilogue ----
    float bv[8];
    *reinterpret_cast<float4*>(&bv[0]) = *reinterpret_cast<const float4*>(bias0 + tc * 4);
    *reinterpret_cast<float4*>(&bv[4]) = *reinterpret_cast<const float4*>(bias0 + 128 + tc * 4);
    if (MODE == 1) {
        float sb[8];
        *reinterpret_cast<float4*>(&sb[0]) = *reinterpret_cast<const float4*>(bias1 + tc * 4);
        *reinterpret_cast<float4*>(&sb[4]) = *reinterpret_cast<const float4*>(bias1 + 128 + tc * 4);
#pragma unroll
        for (int j = 0; j < 8; ++j) bv[j] += sb[j];
    }
#pragma unroll
    for (int i = 0; i < 8; ++i) {
#pragma unroll
        for (int j = 0; j < 8; ++j) {
            float v = acc[i][j] + bv[j];
            if (MODE == 1) v = gelu_exact(v);   // mega: GELU before LN
            acc[i][j] = v;
        }
    }

    // per-row mean/var across the block (row lives in 32 threads of same tr)
    float* red = &Bs[0][0];     // reuse: [0..2047]=sum, [2048..4095]=sumsq
#pragma unroll
    for (int i = 0; i < 8; ++i) {
        float s = 0.f, q = 0.f;
#pragma unroll
        for (int j = 0; j < 8; ++j) { s += acc[i][j]; q += acc[i][j] * acc[i][j]; }
        red[(tr * 8 + i) * 32 + tc]        = s;
        red[2048 + (tr * 8 + i) * 32 + tc] = q;
    }
    __syncthreads();
    float* mbuf = &As[0][0];
    float* rbuf = &As[2][0];
    if (tid < 64) {
        float s = 0.f, q = 0.f;
#pragma unroll
        for (int t = 0; t < 32; ++t) { s += red[tid * 32 + t]; q += red[2048 + tid * 32 + t]; }
        const float mean = s * (1.0f / 256.0f);
        const float var  = q * (1.0f / 256.0f) - mean * mean;
        mbuf[tid] = mean;
        rbuf[tid] = rsqrtf(var + 1e-5f);
    }
    __syncthreads();

    float gv[8], b2v[8];
    *reinterpret_cast<float4*>(&gv[0])  = *reinterpret_cast<const float4*>(lng + tc * 4);
    *reinterpret_cast<float4*>(&gv[4])  = *reinterpret_cast<const float4*>(lng + 128 + tc * 4);
    *reinterpret_cast<float4*>(&b2v[0]) = *reinterpret_cast<const float4*>(lnb + tc * 4);
    *reinterpret_cast<float4*>(&b2v[4]) = *reinterpret_cast<const float4*>(lnb + 128 + tc * 4);

#pragma unroll
    for (int i = 0; i < 8; ++i) {
        const int m = brow + tr * 8 + i;
        if (m >= M) continue;
        const float mu = mbuf[tr * 8 + i];
        const float rs = rbuf[tr * 8 + i];
        float o[8];
#pragma unroll
        for (int j = 0; j < 8; ++j) {
            float v = (acc[i][j] - mu) * rs * gv[j] + b2v[j];
            if (MODE == 0) v = gelu_exact(v);   // pre: GELU after LN
            o[j] = v;
        }
        *reinterpret_cast<float4*>(C + (size_t)m * 256 + tc * 4)       = make_float4(o[0], o[1], o[2], o[3]);
        *reinterpret_cast<float4*>(C + (size_t)m * 256 + 128 + tc * 4) = make_float4(o[4], o[5], o[6], o[7]);
    }
}

// ---------------------------------------------------------------------------
// w~[r][k] = sum_j rel_W[r][k][j] * attn_vec[j]
// ---------------------------------------------------------------------------
__global__ __launch_bounds__(256)
void wtilde_kernel(const float* __restrict__ relW, const float* __restrict__ av,
                   float* __restrict__ wt)
{
    __shared__ float avs[256];
    const int r = blockIdx.x, tid = threadIdx.x;
    avs[tid] = av[tid];
    __syncthreads();
    const float* W = relW + (size_t)r * 65536 + (size_t)tid * 256;
    float s = 0.f;
    for (int j = 0; j < 256; j += 4) {
        const float4 w4 = *reinterpret_cast<const float4*>(W + j);
        s += w4.x * avs[j] + w4.y * avs[j + 1] + w4.z * avs[j + 2] + w4.w * avs[j + 3];
    }
    wt[r * 256 + tid] = s;
}

// ---------------------------------------------------------------------------
// Edge aggregation: one wave per edge; lane handles 4 dims (float4 gather +
// 4 fp32 atomicAdds). agg layout [R][N][256].
// ---------------------------------------------------------------------------
__global__ __launch_bounds__(256)
void edge_agg(const int* __restrict__ rows, const int* __restrict__ cols,
              const float* __restrict__ vals, const float* __restrict__ x,
              float* __restrict__ agg, int RE, int E, int Nn)
{
    const int lane = threadIdx.x & 63;
    const int wid  = blockIdx.x * (blockDim.x >> 6) + (threadIdx.x >> 6);
    const int nw   = gridDim.x * (blockDim.x >> 6);
    for (int e = wid; e < RE; e += nw) {
        const int r   = e / E;
        const int row = rows[e];
        const int col = cols[e];
        const float v = vals[e];
        const float4 xv = reinterpret_cast<const float4*>(x + ((size_t)col << 8))[lane];
        float* ar = agg + (((size_t)r * Nn + row) << 8) + lane * 4;
        atomicAdd(ar + 0, v * xv.x);
        atomicAdd(ar + 1, v * xv.y);
        atomicAdd(ar + 2, v * xv.z);
        atomicAdd(ar + 3, v * xv.w);
    }
}

// ---------------------------------------------------------------------------
// Per-node semantic attention: scores from agg·w~, mask = any(agg!=0),
// masked softmax -> attn_out [N][4]
// ---------------------------------------------------------------------------
__global__ __launch_bounds__(256)
void score_softmax(const float* __restrict__ agg, const float* __restrict__ wt,
                   float* __restrict__ attn_out, int Nn)
{
    const int n = blockIdx.x;
    const int tid = threadIdx.x;
    const int lane = tid & 63, wv = tid >> 6;
    __shared__ float redS[4][4];
    __shared__ int   redZ[4][4];
#pragma unroll
    for (int r = 0; r < 4; ++r) {
        const float v = agg[(((size_t)r * Nn + n) << 8) + tid];
        float p = v * wt[r * 256 + tid];
#pragma unroll
        for (int off = 32; off; off >>= 1) p += __shfl_xor(p, off, 64);
        const int nz = (__ballot(v != 0.0f) != 0ULL) ? 1 : 0;
        if (lane == 0) { redS[r][wv] = p; redZ[r][wv] = nz; }
    }
    __syncthreads();
    if (tid == 0) {
        float sc[4];
        int   z[4];
        float mx = -3.0e38f;
#pragma unroll
        for (int r = 0; r < 4; ++r) {
            const float s = redS[r][0] + redS[r][1] + redS[r][2] + redS[r][3];
            z[r]  = redZ[r][0] | redZ[r][1] | redZ[r][2] | redZ[r][3];
            sc[r] = z[r] ? s : -1e30f;
            mx = fmaxf(mx, sc[r]);
        }
        float ex[4], es = 0.f;
#pragma unroll
        for (int r = 0; r < 4; ++r) { ex[r] = expf(sc[r] - mx); es += ex[r]; }
        const float inv = 1.0f / es;
#pragma unroll
        for (int r = 0; r < 4; ++r)
            attn_out[(size_t)n * 4 + r] = z[r] ? ex[r] * inv : 0.0f;
    }
}

// ---------------------------------------------------------------------------
extern "C" void kernel_launch(void* const* d_in, const int* in_sizes, int n_in,
                              void* d_out, int out_size, void* d_ws, size_t ws_size,
                              hipStream_t stream)
{
    const int*   rows     = (const int*)d_in[0];
    const int*   cols     = (const int*)d_in[1];
    const float* vals     = (const float*)d_in[2];
    const float* node_emb = (const float*)d_in[3];
    const float* pre_W    = (const float*)d_in[4];
    const float* pre_b    = (const float*)d_in[5];
    const float* ln1_g    = (const float*)d_in[6];
    const float* ln1_b    = (const float*)d_in[7];
    const float* rel_W    = (const float*)d_in[8];
    const float* attn_vec = (const float*)d_in[9];
    const float* self_W   = (const float*)d_in[10];
    const float* self_b   = (const float*)d_in[11];
    const float* bias     = (const float*)d_in[12];
    const float* ln2_g    = (const float*)d_in[13];
    const float* ln2_b    = (const float*)d_in[14];

    const int Dd = 256;
    const int R  = in_sizes[8] / (Dd * Dd);   // 4
    const int N  = in_sizes[3] / Dd;          // 50000
    const int E  = in_sizes[0] / R;           // 800000

    float* out  = (float*)d_out;
    float* outF = out;                              // final  [N][256]
    float* outA = out + (size_t)N * Dd;             // attn   [N][4]
    float* outX = outA + (size_t)N * R;             // x_all  [N][256]

    float* S  = (float*)d_ws;                       // agg [R][N][256]  204.8 MB
    float* X  = S + (size_t)R * N * Dd;             // x   [N][256]      51.2 MB
    float* WT = X + (size_t)N * Dd;                 // w~  [R][256]       4 KB

    const int mblocks = (N + 63) / 64;

    // 1. pre-encoder: x = gelu(LN1(node_emb @ pre_W + pre_b))
    gemm_fused<0><<<mblocks, 256, 0, stream>>>(node_emb, nullptr, nullptr, pre_W,
                                               nullptr, pre_b, nullptr, ln1_g, ln1_b,
                                               X, N);
    // 2. zero agg
    hipMemsetAsync(S, 0, (size_t)R * N * Dd * sizeof(float), stream);
    // 3. w~
    wtilde_kernel<<<R, 256, 0, stream>>>(rel_W, attn_vec, WT);
    // 4. sparse aggregation
    edge_agg<<<2048, 256, 0, stream>>>(rows, cols, vals, X, S, R * E, E, N);
    // 5. attention weights -> outA (also consumed by mega-GEMM)
    score_softmax<<<N, 256, 0, stream>>>(S, WT, outA, N);
    // 6. mega-GEMM: final = LN2(gelu([attn*agg | x] @ [rel_W; self_W] + bias + self_b))
    gemm_fused<1><<<mblocks, 256, 0, stream>>>(X, S, outA, rel_W, self_W,
                                               bias, self_b, ln2_g, ln2_b,
                                               outF, N);
    // 7. x_all passthrough
    hipMemcpyAsync(outX, node_emb, (size_t)N * Dd * sizeof(float),
                   hipMemcpyDeviceToDevice, stream);
}

// Round 2
// 1539.301 us; speedup vs baseline: 7.4645x; 7.4645x over previous
//
#include <hip/hip_runtime.h>
#include <math.h>

// ---------------------------------------------------------------------------
// LearnableWeightedRGCN — round 2: CSR-based aggregation (no fp32 atomics).
// N=50000 nodes, D=256, R=4 relations, E=800000 edges/relation.
//
// Pipeline:
//   1. x = gelu(LN1(node_emb @ pre_W + pre_b))            [gemm_fused<0>]
//   2. CSR build: histogram rows -> exclusive scan -> scatter (col,val)
//   3. agg[r][n] = sum_e val*x[col]  (one wave per (r,n), register acc)
//      + fused score[n][r] = agg . w~[r]  with mask sentinel
//   4. attn = masked softmax over 4 scores per node        [softmax4]
//   5. final = LN2(gelu([attn*agg | x] @ [rel_W;self_W] + bias + self_b))
//   6. x_all out = node_emb (D2D copy)
// ---------------------------------------------------------------------------

__device__ __forceinline__ float gelu_exact(float v) {
    return 0.5f * v * (1.0f + erff(v * 0.70710678118654752f));
}

// ---------------------------------------------------------------------------
// Row-block GEMM (unchanged from R1): 64 rows x 256 cols per block,
// 8x8 micro-tile per thread, fused bias/GELU/LN epilogues.
// ---------------------------------------------------------------------------
template<int MODE>
__global__ __launch_bounds__(256)
void gemm_fused(const float* __restrict__ A, const float* __restrict__ agg,
                const float* __restrict__ attn, const float* __restrict__ B0,
                const float* __restrict__ B1, const float* __restrict__ bias0,
                const float* __restrict__ bias1, const float* __restrict__ lng,
                const float* __restrict__ lnb, float* __restrict__ C, int M)
{
    constexpr int K = (MODE == 0) ? 256 : 1280;
    __shared__ float As[16][68];    // padded: k-major, [k][m]
    __shared__ float Bs[16][256];   // [k][n]
    const int tid  = threadIdx.x;
    const int tr   = tid >> 5;          // 0..7
    const int tc   = tid & 31;          // 0..31
    const int brow = blockIdx.x * 64;
    const int lm   = tid >> 2;          // 0..63 (A staging row)
    const int lk   = (tid & 3) << 2;    // 0,4,8,12 (A staging k)
    const int gm   = brow + lm;

    float acc[8][8];
#pragma unroll
    for (int i = 0; i < 8; ++i) {
#pragma unroll
        for (int j = 0; j < 8; ++j) acc[i][j] = 0.0f;
    }

    for (int kt = 0; kt < K; kt += 16) {
        // ---- stage A tile (64 rows x 16 k) ----
        float4 av = make_float4(0.f, 0.f, 0.f, 0.f);
        if (gm < M) {
            const float* src;
            float scale = 1.0f;
            if (MODE == 0) {
                src = A + (size_t)gm * 256 + kt + lk;
            } else {
                if (kt < 1024) {
                    const int r = kt >> 8;
                    src = agg + (((size_t)r * M + gm) << 8) + (kt & 255) + lk;
                    scale = attn[(size_t)gm * 4 + r];
                } else {
                    src = A + (size_t)gm * 256 + (kt - 1024) + lk;
                }
            }
            av = *reinterpret_cast<const float4*>(src);
            av.x *= scale; av.y *= scale; av.z *= scale; av.w *= scale;
        }
        As[lk + 0][lm] = av.x;
        As[lk + 1][lm] = av.y;
        As[lk + 2][lm] = av.z;
        As[lk + 3][lm] = av.w;

        // ---- stage B tile (16 k x 256 n) ----
        {
            const float* Bsrc = (MODE == 0 || kt < 1024)
                                ? (B0 + (size_t)kt * 256)
                                : (B1 + (size_t)(kt - 1024) * 256);
#pragma unroll
            for (int t = 0; t < 4; ++t) {
                const int f  = tid + t * 256;
                const int k  = f >> 6;
                const int n4 = (f & 63) << 2;
                *reinterpret_cast<float4*>(&Bs[k][n4]) =
                    *reinterpret_cast<const float4*>(Bsrc + (size_t)k * 256 + n4);
            }
        }
        __syncthreads();

#pragma unroll
        for (int k = 0; k < 16; ++k) {
            float a[8], b[8];
            *reinterpret_cast<float4*>(&a[0]) = *reinterpret_cast<const float4*>(&As[k][tr * 8]);
            *reinterpret_cast<float4*>(&a[4]) = *reinterpret_cast<const float4*>(&As[k][tr * 8 + 4]);
            *reinterpret_cast<float4*>(&b[0]) = *reinterpret_cast<const float4*>(&Bs[k][tc * 4]);
            *reinterpret_cast<float4*>(&b[4]) = *reinterpret_cast<const float4*>(&Bs[k][128 + tc * 4]);
#pragma unroll
            for (int i = 0; i < 8; ++i) {
#pragma unroll
                for (int j = 0; j < 8; ++j) acc[i][j] = fmaf(a[i], b[j], acc[i][j]);
            }
        }
        __syncthreads();
    }

    // ---- epilogue ----
    float bv[8];
    *reinterpret_cast<float4*>(&bv[0]) = *reinterpret_cast<const float4*>(bias0 + tc * 4);
    *reinterpret_cast<float4*>(&bv[4]) = *reinterpret_cast<const float4*>(bias0 + 128 + tc * 4);
    if (MODE == 1) {
        float sb[8];
        *reinterpret_cast<float4*>(&sb[0]) = *reinterpret_cast<const float4*>(bias1 + tc * 4);
        *reinterpret_cast<float4*>(&sb[4]) = *reinterpret_cast<const float4*>(bias1 + 128 + tc * 4);
#pragma unroll
        for (int j = 0; j < 8; ++j) bv[j] += sb[j];
    }
#pragma unroll
    for (int i = 0; i < 8; ++i) {
#pragma unroll
        for (int j = 0; j < 8; ++j) {
            float v = acc[i][j] + bv[j];
            if (MODE == 1) v = gelu_exact(v);   // mega: GELU before LN
            acc[i][j] = v;
        }
    }

    // per-row mean/var across the block
    float* red = &Bs[0][0];
#pragma unroll
    for (int i = 0; i < 8; ++i) {
        float s = 0.f, q = 0.f;
#pragma unroll
        for (int j = 0; j < 8; ++j) { s += acc[i][j]; q += acc[i][j] * acc[i][j]; }
        red[(tr * 8 + i) * 32 + tc]        = s;
        red[2048 + (tr * 8 + i) * 32 + tc] = q;
    }
    __syncthreads();
    float* mbuf = &As[0][0];
    float* rbuf = &As[2][0];
    if (tid < 64) {
        float s = 0.f, q = 0.f;
#pragma unroll
        for (int t = 0; t < 32; ++t) { s += red[tid * 32 + t]; q += red[2048 + tid * 32 + t]; }
        const float mean = s * (1.0f / 256.0f);
        const float var  = q * (1.0f / 256.0f) - mean * mean;
        mbuf[tid] = mean;
        rbuf[tid] = rsqrtf(var + 1e-5f);
    }
    __syncthreads();

    float gv[8], b2v[8];
    *reinterpret_cast<float4*>(&gv[0])  = *reinterpret_cast<const float4*>(lng + tc * 4);
    *reinterpret_cast<float4*>(&gv[4])  = *reinterpret_cast<const float4*>(lng + 128 + tc * 4);
    *reinterpret_cast<float4*>(&b2v[0]) = *reinterpret_cast<const float4*>(lnb + tc * 4);
    *reinterpret_cast<float4*>(&b2v[4]) = *reinterpret_cast<const float4*>(lnb + 128 + tc * 4);

#pragma unroll
    for (int i = 0; i < 8; ++i) {
        const int m = brow + tr * 8 + i;
        if (m >= M) continue;
        const float mu = mbuf[tr * 8 + i];
        const float rs = rbuf[tr * 8 + i];
        float o[8];
#pragma unroll
        for (int j = 0; j < 8; ++j) {
            float v = (acc[i][j] - mu) * rs * gv[j] + b2v[j];
            if (MODE == 0) v = gelu_exact(v);   // pre: GELU after LN
            o[j] = v;
        }
        *reinterpret_cast<float4*>(C + (size_t)m * 256 + tc * 4)       = make_float4(o[0], o[1], o[2], o[3]);
        *reinterpret_cast<float4*>(C + (size_t)m * 256 + 128 + tc * 4) = make_float4(o[4], o[5], o[6], o[7]);
    }
}

// ---------------------------------------------------------------------------
// w~[r][k] = sum_j rel_W[r][k][j] * attn_vec[j]
// ---------------------------------------------------------------------------
__global__ __launch_bounds__(256)
void wtilde_kernel(const float* __restrict__ relW, const float* __restrict__ av,
                   float* __restrict__ wt)
{
    __shared__ float avs[256];
    const int r = blockIdx.x, tid = threadIdx.x;
    avs[tid] = av[tid];
    __syncthreads();
    const float* W = relW + (size_t)r * 65536 + (size_t)tid * 256;
    float s = 0.f;
    for (int j = 0; j < 256; j += 4) {
        const float4 w4 = *reinterpret_cast<const float4*>(W + j);
        s += w4.x * avs[j] + w4.y * avs[j + 1] + w4.z * avs[j + 2] + w4.w * avs[j + 3];
    }
    wt[r * 256 + tid] = s;
}

// ---------------------------------------------------------------------------
// CSR build step 1: histogram of destination rows. counts layout [R*N].
// ---------------------------------------------------------------------------
__global__ __launch_bounds__(256)
void hist_rows(const int* __restrict__ rows, int* __restrict__ counts,
               int RE, int E, int Nn)
{
    const int stride = gridDim.x * blockDim.x;
    for (int e = blockIdx.x * blockDim.x + threadIdx.x; e < RE; e += stride) {
        const int r = e / E;
        atomicAdd(&counts[r * Nn + rows[e]], 1);
    }
}

// ---------------------------------------------------------------------------
// CSR build step 2: exclusive scan over counts (n = R*N = 200000).
// scan_blocks: 1024 elems/block (256 thr x 4), writes per-elem exclusive
// offsets (block-local) + block total. scan_bsums: single-block scan of the
// block totals. scan_add: add block offset, also mirror into cursor.
// ---------------------------------------------------------------------------
__global__ __launch_bounds__(256)
void scan_blocks(const int* __restrict__ counts, int* __restrict__ offs,
                 int* __restrict__ bsums, int n)
{
    __shared__ int sh[256];
    const int t = threadIdx.x;
    const int base = blockIdx.x * 1024 + t * 4;
    int v[4], s = 0;
#pragma unroll
    for (int j = 0; j < 4; ++j) {
        v[j] = (base + j < n) ? counts[base + j] : 0;
        s += v[j];
    }
    sh[t] = s;
    __syncthreads();
    for (int off = 1; off < 256; off <<= 1) {
        const int x = (t >= off) ? sh[t - off] : 0;
        __syncthreads();
        sh[t] += x;
        __syncthreads();
    }
    int run = sh[t] - s;                 // exclusive prefix within block
    if (t == 255) bsums[blockIdx.x] = sh[255];
#pragma unroll
    for (int j = 0; j < 4; ++j) {
        if (base + j < n) offs[base + j] = run;
        run += v[j];
    }
}

__global__ __launch_bounds__(256)
void scan_bsums(int* __restrict__ bsums, int nblk)
{
    __shared__ int sh[256];
    const int t = threadIdx.x;
    const int v = (t < nblk) ? bsums[t] : 0;
    sh[t] = v;
    __syncthreads();
    for (int off = 1; off < 256; off <<= 1) {
        const int x = (t >= off) ? sh[t - off] : 0;
        __syncthreads();
        sh[t] += x;
        __syncthreads();
    }
    if (t < nblk) bsums[t] = sh[t] - v;  // exclusive
}

__global__ __launch_bounds__(256)
void scan_add(int* __restrict__ offs, int* __restrict__ cursor,
              const int* __restrict__ bsums, int n)
{
    const int i = blockIdx.x * 256 + threadIdx.x;
    if (i >= n) return;
    const int v = offs[i] + bsums[i >> 10];
    offs[i]   = v;
    cursor[i] = v;
}

// ---------------------------------------------------------------------------
// CSR build step 3: scatter packed (col, val) into row buckets.
// ---------------------------------------------------------------------------
__global__ __launch_bounds__(256)
void scatter_edges(const int* __restrict__ rows, const int* __restrict__ cols,
                   const float* __restrict__ vals, int* __restrict__ cursor,
                   unsigned long long* __restrict__ edata, int RE, int E, int Nn)
{
    const int stride = gridDim.x * blockDim.x;
    for (int e = blockIdx.x * blockDim.x + threadIdx.x; e < RE; e += stride) {
        const int r   = e / E;
        const int pos = atomicAdd(&cursor[r * Nn + rows[e]], 1);
        edata[pos] = ((unsigned long long)__float_as_uint(vals[e]) << 32)
                   | (unsigned int)cols[e];
    }
}

// ---------------------------------------------------------------------------
// Aggregation: one wave per (r,n). Lane owns 4 dims (float4). Register
// accumulation over the node's edge list, 2 gathers in flight. Single
// non-atomic store. Fused score = agg . w~[r] (wave reduce) with mask
// sentinel -1e30 for all-zero rows.
// ---------------------------------------------------------------------------
__global__ __launch_bounds__(256)
void agg_csr(const int* __restrict__ offs, const unsigned long long* __restrict__ edata,
             const float* __restrict__ x, const float* __restrict__ wt,
             float* __restrict__ agg, float* __restrict__ scores, int Nn, int RE)
{
    const int wid  = (blockIdx.x << 2) + (threadIdx.x >> 6);   // (r,n) work id
    const int lane = threadIdx.x & 63;
    const int RN   = Nn << 2;
    if (wid >= RN) return;
    const int r = wid / Nn;
    const int n = wid - r * Nn;

    const int start = offs[wid];
    const int end   = (wid + 1 < RN) ? offs[wid + 1] : RE;

    float4 acc = make_float4(0.f, 0.f, 0.f, 0.f);
    int j = start;
    for (; j + 1 < end; j += 2) {
        const unsigned long long e0 = edata[j];
        const unsigned long long e1 = edata[j + 1];
        const int   c0 = (int)(e0 & 0xffffffffu);
        const int   c1 = (int)(e1 & 0xffffffffu);
        const float v0 = __uint_as_float((unsigned int)(e0 >> 32));
        const float v1 = __uint_as_float((unsigned int)(e1 >> 32));
        const float4 x0 = reinterpret_cast<const float4*>(x + ((size_t)c0 << 8))[lane];
        const float4 x1 = reinterpret_cast<const float4*>(x + ((size_t)c1 << 8))[lane];
        acc.x = fmaf(v0, x0.x, acc.x); acc.y = fmaf(v0, x0.y, acc.y);
        acc.z = fmaf(v0, x0.z, acc.z); acc.w = fmaf(v0, x0.w, acc.w);
        acc.x = fmaf(v1, x1.x, acc.x); acc.y = fmaf(v1, x1.y, acc.y);
        acc.z = fmaf(v1, x1.z, acc.z); acc.w = fmaf(v1, x1.w, acc.w);
    }
    if (j < end) {
        const unsigned long long e0 = edata[j];
        const int   c0 = (int)(e0 & 0xffffffffu);
        const float v0 = __uint_as_float((unsigned int)(e0 >> 32));
        const float4 x0 = reinterpret_cast<const float4*>(x + ((size_t)c0 << 8))[lane];
        acc.x = fmaf(v0, x0.x, acc.x); acc.y = fmaf(v0, x0.y, acc.y);
        acc.z = fmaf(v0, x0.z, acc.z); acc.w = fmaf(v0, x0.w, acc.w);
    }

    reinterpret_cast<float4*>(agg + ((size_t)wid << 8))[lane] = acc;

    // fused score + mask
    const float4 w4 = reinterpret_cast<const float4*>(wt + (r << 8))[lane];
    float p = acc.x * w4.x + acc.y * w4.y + acc.z * w4.z + acc.w * w4.w;
#pragma unroll
    for (int off = 32; off; off >>= 1) p += __shfl_xor(p, off, 64);
    const bool nz = (acc.x != 0.f) | (acc.y != 0.f) | (acc.z != 0.f) | (acc.w != 0.f);
    const unsigned long long b = __ballot(nz);
    if (lane == 0) scores[(size_t)n * 4 + r] = b ? p : -1e30f;
}

// ---------------------------------------------------------------------------
// Per-node masked softmax over 4 relation scores.
// ---------------------------------------------------------------------------
__global__ __launch_bounds__(256)
void softmax4(const float* __restrict__ scores, float* __restrict__ attn, int Nn)
{
    const int n = blockIdx.x * 256 + threadIdx.x;
    if (n >= Nn) return;
    const float4 s4 = *reinterpret_cast<const float4*>(scores + (size_t)n * 4);
    float s[4] = { s4.x, s4.y, s4.z, s4.w };
    float mx = -3.0e38f;
#pragma unroll
    for (int r = 0; r < 4; ++r) mx = fmaxf(mx, s[r]);
    float ex[4], es = 0.f;
#pragma unroll
    for (int r = 0; r < 4; ++r) { ex[r] = expf(s[r] - mx); es += ex[r]; }
    const float inv = 1.0f / es;
    float4 o;
    o.x = (s[0] > -1e29f) ? ex[0] * inv : 0.0f;
    o.y = (s[1] > -1e29f) ? ex[1] * inv : 0.0f;
    o.z = (s[2] > -1e29f) ? ex[2] * inv : 0.0f;
    o.w = (s[3] > -1e29f) ? ex[3] * inv : 0.0f;
    *reinterpret_cast<float4*>(attn + (size_t)n * 4) = o;
}

// ---------------------------------------------------------------------------
extern "C" void kernel_launch(void* const* d_in, const int* in_sizes, int n_in,
                              void* d_out, int out_size, void* d_ws, size_t ws_size,
                              hipStream_t stream)
{
    const int*   rows     = (const int*)d_in[0];
    const int*   cols     = (const int*)d_in[1];
    const float* vals     = (const float*)d_in[2];
    const float* node_emb = (const float*)d_in[3];
    const float* pre_W    = (const float*)d_in[4];
    const float* pre_b    = (const float*)d_in[5];
    const float* ln1_g    = (const float*)d_in[6];
    const float* ln1_b    = (const float*)d_in[7];
    const float* rel_W    = (const float*)d_in[8];
    const float* attn_vec = (const float*)d_in[9];
    const float* self_W   = (const float*)d_in[10];
    const float* self_b   = (const float*)d_in[11];
    const float* bias     = (const float*)d_in[12];
    const float* ln2_g    = (const float*)d_in[13];
    const float* ln2_b    = (const float*)d_in[14];

    const int Dd = 256;
    const int R  = in_sizes[8] / (Dd * Dd);   // 4
    const int N  = in_sizes[3] / Dd;          // 50000
    const int E  = in_sizes[0] / R;           // 800000
    const int RE = R * E;                     // 3.2M
    const int RN = R * N;                     // 200000

    float* out  = (float*)d_out;
    float* outF = out;                              // final  [N][256]
    float* outA = out + (size_t)N * Dd;             // attn   [N][4]
    float* outX = outA + (size_t)N * R;             // x_all  [N][256]

    // workspace layout
    float* S   = (float*)d_ws;                      // agg [R][N][256]  204.8 MB
    float* X   = S + (size_t)RN * Dd;               // x   [N][256]      51.2 MB
    float* WT  = X + (size_t)N * Dd;                // w~  [R][256]       4 KB
    float* SC  = WT + R * Dd;                       // scores [N][4]    800 KB
    int*   counts = (int*)(SC + (size_t)N * R);     // [RN]             800 KB
    int*   offs   = counts + RN;                    // [RN]             800 KB
    int*   cursor = offs + RN;                      // [RN]             800 KB
    int*   bsums  = cursor + RN;                    // [256]              1 KB
    unsigned long long* edata =
        (unsigned long long*)(((uintptr_t)(bsums + 256) + 255) & ~(uintptr_t)255);
                                                    // [RE] packed       25.6 MB

    const int mblocks = (N + 63) / 64;
    const int nblk    = (RN + 1023) / 1024;         // 196

    // 1. pre-encoder: x = gelu(LN1(node_emb @ pre_W + pre_b))
    gemm_fused<0><<<mblocks, 256, 0, stream>>>(node_emb, nullptr, nullptr, pre_W,
                                               nullptr, pre_b, nullptr, ln1_g, ln1_b,
                                               X, N);
    // 2. w~
    wtilde_kernel<<<R, 256, 0, stream>>>(rel_W, attn_vec, WT);

    // 3. CSR build
    hipMemsetAsync(counts, 0, (size_t)RN * sizeof(int), stream);
    hist_rows<<<2048, 256, 0, stream>>>(rows, counts, RE, E, N);
    scan_blocks<<<nblk, 256, 0, stream>>>(counts, offs, bsums, RN);
    scan_bsums<<<1, 256, 0, stream>>>(bsums, nblk);
    scan_add<<<(RN + 255) / 256, 256, 0, stream>>>(offs, cursor, bsums, RN);
    scatter_edges<<<2048, 256, 0, stream>>>(rows, cols, vals, cursor, edata, RE, E, N);

    // 4. aggregation + fused scores (one wave per (r,n))
    agg_csr<<<(RN + 3) / 4, 256, 0, stream>>>(offs, edata, X, WT, S, SC, N, RE);

    // 5. masked softmax -> attn (outA)
    softmax4<<<(N + 255) / 256, 256, 0, stream>>>(SC, outA, N);

    // 6. mega-GEMM: final = LN2(gelu([attn*agg | x] @ [rel_W; self_W] + bias + self_b))
    gemm_fused<1><<<mblocks, 256, 0, stream>>>(X, S, outA, rel_W, self_W,
                                               bias, self_b, ln2_g, ln2_b,
                                               outF, N);
    // 7. x_all passthrough
    hipMemcpyAsync(outX, node_emb, (size_t)N * Dd * sizeof(float),
                   hipMemcpyDeviceToDevice, stream);
}

// Round 3
// 995.220 us; speedup vs baseline: 11.5454x; 1.5467x over previous
//
#include <hip/hip_runtime.h>
#include <math.h>

// ---------------------------------------------------------------------------
// LearnableWeightedRGCN — round 3: bf16 MFMA GEMMs + bf16 sparse path.
// N=50000, D=256, R=4, E=800000.
//
//   1. build_bt: B-matrices -> bf16, transposed to [n][k]
//   2. gemm_mfma<0>: X = gelu(LN1(node_emb @ pre_W + pre_b))  -> bf16 X
//   3. CSR build (hist/scan/scatter)  [unchanged]
//   4. agg_csr: bf16 gather, f32 acc, bf16 agg store + f32 scores/mask
//   5. softmax4 -> attn (outA)
//   6. gemm_mfma<1>: final = LN2(gelu([attn*agg | x] @ [rel_W;self_W] + b))
//      (attn scaling applied at K-segment boundaries in the accumulator)
//   7. x_all = node_emb (D2D copy)
// ---------------------------------------------------------------------------

typedef __attribute__((ext_vector_type(8))) short bf16x8;
typedef __attribute__((ext_vector_type(4))) float f32x4;

__device__ __forceinline__ float gelu_exact(float v) {
    return 0.5f * v * (1.0f + erff(v * 0.70710678118654752f));
}
__device__ __forceinline__ unsigned short f2bf(float f) {   // RNE
    unsigned u = __float_as_uint(f);
    return (unsigned short)((u + 0x7fffu + ((u >> 16) & 1u)) >> 16);
}
__device__ __forceinline__ unsigned pack2(float a, float b) {
    return (unsigned)f2bf(a) | ((unsigned)f2bf(b) << 16);
}

// ---------------------------------------------------------------------------
// B-matrix prep: BTm[n][k] (k<1024: rel_W[k>>8][k&255][n], else self_W),
// BTp[n][k] = pre_W[k][n]; both bf16.
// ---------------------------------------------------------------------------
__global__ __launch_bounds__(256)
void build_bt(const float* __restrict__ relW, const float* __restrict__ selfW,
              const float* __restrict__ preW, unsigned short* __restrict__ BTm,
              unsigned short* __restrict__ BTp)
{
    const int idx = blockIdx.x * 256 + threadIdx.x;
    if (idx < 1280 * 256) {
        const int k = idx >> 8, n = idx & 255;
        const float v = (k < 1024)
            ? relW[(size_t)(k >> 8) * 65536 + (size_t)(k & 255) * 256 + n]
            : selfW[(size_t)(k - 1024) * 256 + n];
        BTm[(size_t)n * 1280 + k] = f2bf(v);
    } else {
        const int i2 = idx - 1280 * 256;
        if (i2 < 256 * 256) {
            const int k = i2 >> 8, n = i2 & 255;
            BTp[(size_t)n * 256 + k] = f2bf(preW[(size_t)k * 256 + n]);
        }
    }
}

// ---------------------------------------------------------------------------
// MFMA GEMM, BM=64 x BN=256, BK=32, 256 threads (4 waves, each 64x64 out).
// Fragment k-mapping: k = 8*(lane>>4) + j  (consistent for A and B ->
// result invariant to HW k-grouping). m/n index = lane&15 (HW-verified).
// LDS rows of 64B (32 bf16), 16B granules XOR-swizzled: g' = g ^ ((row>>2)&3)
// -> all ds reads/writes <=2-way bank aliased (free).
// MODE 0: A=node_emb f32, K=256, C = gelu(LN1(.+pre_b)) -> bf16 XOut
// MODE 1: A=[agg r=0..3 | x] bf16, K=1280; acc reset per 256-K segment,
//         tot += attn[m][r]*acc; C = LN2(gelu(tot + bias + self_b)) -> f32
// ---------------------------------------------------------------------------
template<int MODE>
__global__ __launch_bounds__(256)
void gemm_mfma(const float* __restrict__ A32,
               const unsigned short* __restrict__ AGG,
               const unsigned short* __restrict__ XB,
               const float* __restrict__ attn,
               const unsigned short* __restrict__ BT,
               const float* __restrict__ bias0, const float* __restrict__ bias1,
               const float* __restrict__ lng, const float* __restrict__ lnb,
               float* __restrict__ Cout, unsigned short* __restrict__ XOut,
               int M, int Nn)
{
    constexpr int K  = MODE ? 1280 : 256;
    constexpr int KT = K / 32;                 // 40 or 8 tiles

    __shared__ __align__(16) unsigned char smA[64 * 64];     // 4 KB
    __shared__ __align__(16) unsigned char smB[256 * 64];    // 16 KB
    __shared__ float redS[4][64];
    __shared__ float redQ[4][64];

    const int tid  = threadIdx.x;
    const int wave = tid >> 6;
    const int l    = tid & 63;
    const int brow = blockIdx.x * 64;

    // staging geometry (writer side)
    const int am   = tid >> 2;                 // A row 0..63 (B: +p*64)
    const int swzg = (tid & 3) ^ ((tid >> 4) & 3);
    unsigned char* dstA = smA + am * 64 + swzg * 16;
    const int arowc = min(brow + am, M - 1);   // clamp: stay in-bounds
    // fragment-read geometry
    const int fragg = (l >> 4) ^ ((l & 15) >> 2);
    const unsigned char* aRd = smA + (l & 15) * 64 + fragg * 16;
    const unsigned char* bRd = smB + (wave * 64 + (l & 15)) * 64 + fragg * 16;

    f32x4 acc[4][4];
    f32x4 tot[4][4];
#pragma unroll
    for (int i = 0; i < 4; ++i)
#pragma unroll
        for (int j = 0; j < 4; ++j) {
            acc[i][j] = f32x4{0.f, 0.f, 0.f, 0.f};
            if (MODE == 1) tot[i][j] = f32x4{0.f, 0.f, 0.f, 0.f};
        }

    // ---- staging loaders (into regs) ----
    uint4 aR;             // mode1 / packed mode0
    float4 aF0, aF1;      // mode0 raw
    uint4 bR[4];

    auto loadA = [&](int kt) {
        const int ke = kt * 32 + (tid & 3) * 8;            // element offset
        if (MODE == 0) {
            const float* p = A32 + (size_t)arowc * 256 + ke;
            aF0 = *reinterpret_cast<const float4*>(p);
            aF1 = *reinterpret_cast<const float4*>(p + 4);
        } else {
            const int seg = kt >> 3;
            const unsigned short* p;
            if (seg < 4)
                p = AGG + (((size_t)seg * Nn + arowc) << 8) + (ke & 255);
            else
                p = XB + ((size_t)arowc << 8) + (ke - 1024);
            aR = *reinterpret_cast<const uint4*>(p);
        }
    };
    auto loadB = [&](int kt) {
#pragma unroll
        for (int p = 0; p < 4; ++p) {
            const int bn = p * 64 + (tid >> 2);
            bR[p] = *reinterpret_cast<const uint4*>(
                BT + (size_t)bn * K + kt * 32 + (tid & 3) * 8);
        }
    };

    loadA(0); loadB(0);

    for (int kt = 0; kt < KT; ++kt) {
        __syncthreads();   // previous tile's reads complete
        if (MODE == 0) {
            uint4 w;
            w.x = pack2(aF0.x, aF0.y); w.y = pack2(aF0.z, aF0.w);
            w.z = pack2(aF1.x, aF1.y); w.w = pack2(aF1.z, aF1.w);
            *reinterpret_cast<uint4*>(dstA) = w;
        } else {
            *reinterpret_cast<uint4*>(dstA) = aR;
        }
#pragma unroll
        for (int p = 0; p < 4; ++p)
            *reinterpret_cast<uint4*>(smB + (p * 64 + (tid >> 2)) * 64 + swzg * 16) = bR[p];
        __syncthreads();   // tile visible

        if (kt + 1 < KT) { loadA(kt + 1); loadB(kt + 1); }

        bf16x8 afr[4], bfr[4];
#pragma unroll
        for (int mb = 0; mb < 4; ++mb)
            afr[mb] = *reinterpret_cast<const bf16x8*>(aRd + mb * 1024);
#pragma unroll
        for (int nb = 0; nb < 4; ++nb)
            bfr[nb] = *reinterpret_cast<const bf16x8*>(bRd + nb * 1024);
#pragma unroll
        for (int mb = 0; mb < 4; ++mb)
#pragma unroll
            for (int nb = 0; nb < 4; ++nb)
                acc[mb][nb] = __builtin_amdgcn_mfma_f32_16x16x32_bf16(
                    afr[mb], bfr[nb], acc[mb][nb], 0, 0, 0);

        if (MODE == 1 && (kt & 7) == 7) {
            const int seg = kt >> 3;
#pragma unroll
            for (int mb = 0; mb < 4; ++mb)
#pragma unroll
                for (int reg = 0; reg < 4; ++reg) {
                    const int row = brow + 16 * mb + 4 * (l >> 4) + reg;
                    const int rc  = min(row, M - 1);
                    const float s = (seg < 4) ? attn[(size_t)rc * 4 + seg] : 1.0f;
#pragma unroll
                    for (int nb = 0; nb < 4; ++nb) {
                        tot[mb][nb][reg] += s * acc[mb][nb][reg];
                        acc[mb][nb][reg] = 0.f;
                    }
                }
        }
    }

    // ---- epilogue ----
    // values: MODE1 -> tot, MODE0 -> acc.  Add bias, (mode1: gelu), LN stats.
    float bb[4], gW[4], bW[4];
#pragma unroll
    for (int nb = 0; nb < 4; ++nb) {
        const int n = wave * 64 + 16 * nb + (l & 15);
        bb[nb] = bias0[n] + (MODE == 1 ? bias1[n] : 0.f);
        gW[nb] = lng[n];
        bW[nb] = lnb[n];
    }
#pragma unroll
    for (int mb = 0; mb < 4; ++mb)
#pragma unroll
        for (int nb = 0; nb < 4; ++nb)
#pragma unroll
            for (int reg = 0; reg < 4; ++reg) {
                float v = (MODE == 1 ? tot[mb][nb][reg] : acc[mb][nb][reg]) + bb[nb];
                if (MODE == 1) v = gelu_exact(v);
                if (MODE == 1) tot[mb][nb][reg] = v; else acc[mb][nb][reg] = v;
            }

    float sS[4][4], sQ[4][4];
#pragma unroll
    for (int mb = 0; mb < 4; ++mb)
#pragma unroll
        for (int reg = 0; reg < 4; ++reg) { sS[mb][reg] = 0.f; sQ[mb][reg] = 0.f; }
#pragma unroll
    for (int mb = 0; mb < 4; ++mb)
#pragma unroll
        for (int nb = 0; nb < 4; ++nb)
#pragma unroll
            for (int reg = 0; reg < 4; ++reg) {
                const float v = (MODE == 1 ? tot[mb][nb][reg] : acc[mb][nb][reg]);
                sS[mb][reg] += v;
                sQ[mb][reg] += v * v;
            }
#pragma unroll
    for (int mb = 0; mb < 4; ++mb)
#pragma unroll
        for (int reg = 0; reg < 4; ++reg) {
#pragma unroll
            for (int off = 1; off < 16; off <<= 1) {
                sS[mb][reg] += __shfl_xor(sS[mb][reg], off, 64);
                sQ[mb][reg] += __shfl_xor(sQ[mb][reg], off, 64);
            }
        }
    if ((l & 15) == 0) {
        const int g = l >> 4;
#pragma unroll
        for (int mb = 0; mb < 4; ++mb)
#pragma unroll
            for (int reg = 0; reg < 4; ++reg) {
                redS[wave][mb * 16 + g * 4 + reg] = sS[mb][reg];
                redQ[wave][mb * 16 + g * 4 + reg] = sQ[mb][reg];
            }
    }
    __syncthreads();
    if (tid < 64) {
        float s = 0.f, q = 0.f;
#pragma unroll
        for (int w = 0; w < 4; ++w) { s += redS[w][tid]; q += redQ[w][tid]; }
        const float mean = s * (1.0f / 256.0f);
        const float var  = q * (1.0f / 256.0f) - mean * mean;
        redS[0][tid] = mean;
        redQ[0][tid] = rsqrtf(var + 1e-5f);
    }
    __syncthreads();

#pragma unroll
    for (int mb = 0; mb < 4; ++mb)
#pragma unroll
        for (int reg = 0; reg < 4; ++reg) {
            const int r16 = mb * 16 + (l >> 4) * 4 + reg;
            const int row = brow + r16;
            if (row >= M) continue;
            const float mu = redS[0][r16];
            const float rs = redQ[0][r16];
#pragma unroll
            for (int nb = 0; nb < 4; ++nb) {
                const int n = wave * 64 + 16 * nb + (l & 15);
                const float e = (MODE == 1 ? tot[mb][nb][reg] : acc[mb][nb][reg]);
                float v = (e - mu) * rs * gW[nb] + bW[nb];
                if (MODE == 0) {
                    XOut[(size_t)row * 256 + n] = f2bf(gelu_exact(v));
                } else {
                    Cout[(size_t)row * 256 + n] = v;
                }
            }
        }
}

// ---------------------------------------------------------------------------
// w~[r][k] = sum_j rel_W[r][k][j] * attn_vec[j]   (fp32)
// ---------------------------------------------------------------------------
__global__ __launch_bounds__(256)
void wtilde_kernel(const float* __restrict__ relW, const float* __restrict__ av,
                   float* __restrict__ wt)
{
    __shared__ float avs[256];
    const int r = blockIdx.x, tid = threadIdx.x;
    avs[tid] = av[tid];
    __syncthreads();
    const float* W = relW + (size_t)r * 65536 + (size_t)tid * 256;
    float s = 0.f;
    for (int j = 0; j < 256; j += 4) {
        const float4 w4 = *reinterpret_cast<const float4*>(W + j);
        s += w4.x * avs[j] + w4.y * avs[j + 1] + w4.z * avs[j + 2] + w4.w * avs[j + 3];
    }
    wt[r * 256 + tid] = s;
}

// ---------------------------------------------------------------------------
// CSR build (unchanged from R2)
// ---------------------------------------------------------------------------
__global__ __launch_bounds__(256)
void hist_rows(const int* __restrict__ rows, int* __restrict__ counts,
               int RE, int E, int Nn)
{
    const int stride = gridDim.x * blockDim.x;
    for (int e = blockIdx.x * blockDim.x + threadIdx.x; e < RE; e += stride) {
        const int r = e / E;
        atomicAdd(&counts[r * Nn + rows[e]], 1);
    }
}

__global__ __launch_bounds__(256)
void scan_blocks(const int* __restrict__ counts, int* __restrict__ offs,
                 int* __restrict__ bsums, int n)
{
    __shared__ int sh[256];
    const int t = threadIdx.x;
    const int base = blockIdx.x * 1024 + t * 4;
    int v[4], s = 0;
#pragma unroll
    for (int j = 0; j < 4; ++j) {
        v[j] = (base + j < n) ? counts[base + j] : 0;
        s += v[j];
    }
    sh[t] = s;
    __syncthreads();
    for (int off = 1; off < 256; off <<= 1) {
        const int x = (t >= off) ? sh[t - off] : 0;
        __syncthreads();
        sh[t] += x;
        __syncthreads();
    }
    int run = sh[t] - s;
    if (t == 255) bsums[blockIdx.x] = sh[255];
#pragma unroll
    for (int j = 0; j < 4; ++j) {
        if (base + j < n) offs[base + j] = run;
        run += v[j];
    }
}

__global__ __launch_bounds__(256)
void scan_bsums(int* __restrict__ bsums, int nblk)
{
    __shared__ int sh[256];
    const int t = threadIdx.x;
    const int v = (t < nblk) ? bsums[t] : 0;
    sh[t] = v;
    __syncthreads();
    for (int off = 1; off < 256; off <<= 1) {
        const int x = (t >= off) ? sh[t - off] : 0;
        __syncthreads();
        sh[t] += x;
        __syncthreads();
    }
    if (t < nblk) bsums[t] = sh[t] - v;
}

__global__ __launch_bounds__(256)
void scan_add(int* __restrict__ offs, int* __restrict__ cursor,
              const int* __restrict__ bsums, int n)
{
    const int i = blockIdx.x * 256 + threadIdx.x;
    if (i >= n) return;
    const int v = offs[i] + bsums[i >> 10];
    offs[i]   = v;
    cursor[i] = v;
}

__global__ __launch_bounds__(256)
void scatter_edges(const int* __restrict__ rows, const int* __restrict__ cols,
                   const float* __restrict__ vals, int* __restrict__ cursor,
                   unsigned long long* __restrict__ edata, int RE, int E, int Nn)
{
    const int stride = gridDim.x * blockDim.x;
    for (int e = blockIdx.x * blockDim.x + threadIdx.x; e < RE; e += stride) {
        const int r   = e / E;
        const int pos = atomicAdd(&cursor[r * Nn + rows[e]], 1);
        edata[pos] = ((unsigned long long)__float_as_uint(vals[e]) << 32)
                   | (unsigned int)cols[e];
    }
}

// ---------------------------------------------------------------------------
// Aggregation: one wave per (r,n). bf16 gather (8B/lane), f32 acc, 4-deep
// edge pipeline. Stores agg bf16 + fused f32 score with mask sentinel.
// ---------------------------------------------------------------------------
__global__ __launch_bounds__(256)
void agg_csr(const int* __restrict__ offs, const unsigned long long* __restrict__ edata,
             const unsigned short* __restrict__ x, const float* __restrict__ wt,
             unsigned short* __restrict__ agg, float* __restrict__ scores,
             int Nn, int RE)
{
    const int wid  = (blockIdx.x << 2) + (threadIdx.x >> 6);
    const int lane = threadIdx.x & 63;
    const int RN   = Nn << 2;
    if (wid >= RN) return;
    const int r = wid / Nn;
    const int n = wid - r * Nn;

    const int start = offs[wid];
    const int end   = (wid + 1 < RN) ? offs[wid + 1] : RE;

    float ax = 0.f, ay = 0.f, az = 0.f, aw = 0.f;
    int j = start;
    for (; j + 3 < end; j += 4) {
        unsigned long long e[4];
        uint2 d[4];
        float v[4];
#pragma unroll
        for (int q = 0; q < 4; ++q) e[q] = edata[j + q];
#pragma unroll
        for (int q = 0; q < 4; ++q) {
            const int c = (int)(e[q] & 0xffffffffu);
            v[q] = __uint_as_float((unsigned)(e[q] >> 32));
            d[q] = *reinterpret_cast<const uint2*>(x + ((size_t)c << 8) + lane * 4);
        }
#pragma unroll
        for (int q = 0; q < 4; ++q) {
            ax = fmaf(v[q], __uint_as_float(d[q].x << 16),          ax);
            ay = fmaf(v[q], __uint_as_float(d[q].x & 0xffff0000u),  ay);
            az = fmaf(v[q], __uint_as_float(d[q].y << 16),          az);
            aw = fmaf(v[q], __uint_as_float(d[q].y & 0xffff0000u),  aw);
        }
    }
    for (; j < end; ++j) {
        const unsigned long long e0 = edata[j];
        const int   c0 = (int)(e0 & 0xffffffffu);
        const float v0 = __uint_as_float((unsigned)(e0 >> 32));
        const uint2 d0 = *reinterpret_cast<const uint2*>(x + ((size_t)c0 << 8) + lane * 4);
        ax = fmaf(v0, __uint_as_float(d0.x << 16),         ax);
        ay = fmaf(v0, __uint_as_float(d0.x & 0xffff0000u), ay);
        az = fmaf(v0, __uint_as_float(d0.y << 16),         az);
        aw = fmaf(v0, __uint_as_float(d0.y & 0xffff0000u), aw);
    }

    uint2 st;
    st.x = pack2(ax, ay);
    st.y = pack2(az, aw);
    *reinterpret_cast<uint2*>(agg + ((size_t)wid << 8) + lane * 4) = st;

    const float4 w4 = reinterpret_cast<const float4*>(wt + (r << 8))[lane];
    float p = ax * w4.x + ay * w4.y + az * w4.z + aw * w4.w;
#pragma unroll
    for (int off = 32; off; off >>= 1) p += __shfl_xor(p, off, 64);
    const bool nz = (ax != 0.f) | (ay != 0.f) | (az != 0.f) | (aw != 0.f);
    const unsigned long long b = __ballot(nz);
    if (lane == 0) scores[(size_t)n * 4 + r] = b ? p : -1e30f;
}

// ---------------------------------------------------------------------------
// Per-node masked softmax over 4 relation scores.
// ---------------------------------------------------------------------------
__global__ __launch_bounds__(256)
void softmax4(const float* __restrict__ scores, float* __restrict__ attn, int Nn)
{
    const int n = blockIdx.x * 256 + threadIdx.x;
    if (n >= Nn) return;
    const float4 s4 = *reinterpret_cast<const float4*>(scores + (size_t)n * 4);
    float s[4] = { s4.x, s4.y, s4.z, s4.w };
    float mx = -3.0e38f;
#pragma unroll
    for (int r = 0; r < 4; ++r) mx = fmaxf(mx, s[r]);
    float ex[4], es = 0.f;
#pragma unroll
    for (int r = 0; r < 4; ++r) { ex[r] = expf(s[r] - mx); es += ex[r]; }
    const float inv = 1.0f / es;
    float4 o;
    o.x = (s[0] > -1e29f) ? ex[0] * inv : 0.0f;
    o.y = (s[1] > -1e29f) ? ex[1] * inv : 0.0f;
    o.z = (s[2] > -1e29f) ? ex[2] * inv : 0.0f;
    o.w = (s[3] > -1e29f) ? ex[3] * inv : 0.0f;
    *reinterpret_cast<float4*>(attn + (size_t)n * 4) = o;
}

// ---------------------------------------------------------------------------
extern "C" void kernel_launch(void* const* d_in, const int* in_sizes, int n_in,
                              void* d_out, int out_size, void* d_ws, size_t ws_size,
                              hipStream_t stream)
{
    const int*   rows     = (const int*)d_in[0];
    const int*   cols     = (const int*)d_in[1];
    const float* vals     = (const float*)d_in[2];
    const float* node_emb = (const float*)d_in[3];
    const float* pre_W    = (const float*)d_in[4];
    const float* pre_b    = (const float*)d_in[5];
    const float* ln1_g    = (const float*)d_in[6];
    const float* ln1_b    = (const float*)d_in[7];
    const float* rel_W    = (const float*)d_in[8];
    const float* attn_vec = (const float*)d_in[9];
    const float* self_W   = (const float*)d_in[10];
    const float* self_b   = (const float*)d_in[11];
    const float* bias     = (const float*)d_in[12];
    const float* ln2_g    = (const float*)d_in[13];
    const float* ln2_b    = (const float*)d_in[14];

    const int Dd = 256;
    const int R  = in_sizes[8] / (Dd * Dd);   // 4
    const int N  = in_sizes[3] / Dd;          // 50000
    const int E  = in_sizes[0] / R;           // 800000
    const int RE = R * E;
    const int RN = R * N;

    float* out  = (float*)d_out;
    float* outF = out;                              // final  [N][256] f32
    float* outA = out + (size_t)N * Dd;             // attn   [N][4]   f32
    float* outX = outA + (size_t)N * R;             // x_all  [N][256] f32

    // workspace layout (256B-aligned chunks)
    char* w = (char*)d_ws;
    auto alloc = [&](size_t bytes) {
        char* p = w;
        w += (bytes + 255) & ~(size_t)255;
        return p;
    };
    unsigned short* AGG = (unsigned short*)alloc((size_t)RN * Dd * 2);   // 102.4 MB
    unsigned short* XB  = (unsigned short*)alloc((size_t)N * Dd * 2);    //  25.6 MB
    unsigned short* BTm = (unsigned short*)alloc((size_t)Dd * 1280 * 2); // 655 KB
    unsigned short* BTp = (unsigned short*)alloc((size_t)Dd * Dd * 2);   // 131 KB
    float* WT  = (float*)alloc((size_t)R * Dd * 4);
    float* SC  = (float*)alloc((size_t)N * R * 4);
    int* counts = (int*)alloc((size_t)RN * 4);
    int* offs   = (int*)alloc((size_t)RN * 4);
    int* cursor = (int*)alloc((size_t)RN * 4);
    int* bsums  = (int*)alloc(1024);
    unsigned long long* edata = (unsigned long long*)alloc((size_t)RE * 8); // 25.6 MB

    const int mblocks = (N + 63) / 64;              // 782
    const int nblk    = (RN + 1023) / 1024;         // 196

    // 1. B-matrix prep
    build_bt<<<(1280 * 256 + 256 * 256 + 255) / 256, 256, 0, stream>>>(
        rel_W, self_W, pre_W, BTm, BTp);

    // 2. pre-encoder -> X bf16
    gemm_mfma<0><<<mblocks, 256, 0, stream>>>(node_emb, nullptr, nullptr, nullptr,
                                              BTp, pre_b, nullptr, ln1_g, ln1_b,
                                              nullptr, XB, N, N);
    // 3. w~
    wtilde_kernel<<<R, 256, 0, stream>>>(rel_W, attn_vec, WT);

    // 4. CSR build
    hipMemsetAsync(counts, 0, (size_t)RN * sizeof(int), stream);
    hist_rows<<<2048, 256, 0, stream>>>(rows, counts, RE, E, N);
    scan_blocks<<<nblk, 256, 0, stream>>>(counts, offs, bsums, RN);
    scan_bsums<<<1, 256, 0, stream>>>(bsums, nblk);
    scan_add<<<(RN + 255) / 256, 256, 0, stream>>>(offs, cursor, bsums, RN);
    scatter_edges<<<2048, 256, 0, stream>>>(rows, cols, vals, cursor, edata, RE, E, N);

    // 5. aggregation + fused scores
    agg_csr<<<(RN + 3) / 4, 256, 0, stream>>>(offs, edata, XB, WT, AGG, SC, N, RE);

    // 6. masked softmax -> attn (outA)
    softmax4<<<(N + 255) / 256, 256, 0, stream>>>(SC, outA, N);

    // 7. mega-GEMM -> final (outF)
    gemm_mfma<1><<<mblocks, 256, 0, stream>>>(nullptr, AGG, XB, outA,
                                              BTm, bias, self_b, ln2_g, ln2_b,
                                              outF, nullptr, N, N);
    // 8. x_all passthrough
    hipMemcpyAsync(outX, node_emb, (size_t)N * Dd * sizeof(float),
                   hipMemcpyDeviceToDevice, stream);
}

// Round 4
// 813.278 us; speedup vs baseline: 14.1282x; 1.2237x over previous
//
#include <hip/hip_runtime.h>
#include <math.h>

// ---------------------------------------------------------------------------
// LearnableWeightedRGCN — round 4.
// Key changes vs R3:
//  * attn-scaling moved OUT of the mega-GEMM: scores computed edge-wise from
//    y[n][r]=x[n]·w~[r] BEFORE aggregation; agg_csr stores attn-scaled bf16.
//    -> GEMM needs one accumulator (64 AGPR, was 128) -> 3x occupancy.
//  * GEMM restructured: 128x256 tile, 8 waves, BK=64, global_load_lds(16B)
//    staging with XOR-(row&7) source pre-swizzle, 2-barrier loop (m97-style).
//  * conv_emb: node_emb -> bf16 A-matrix + f32 x_all output in one pass.
// ---------------------------------------------------------------------------

typedef __attribute__((ext_vector_type(8))) short bf16x8;
typedef __attribute__((ext_vector_type(4))) float f32x4;
typedef unsigned long long u64;

__device__ __forceinline__ float gelu_exact(float v) {
    return 0.5f * v * (1.0f + erff(v * 0.70710678118654752f));
}
__device__ __forceinline__ unsigned short f2bf(float f) {   // RNE
    unsigned u = __float_as_uint(f);
    return (unsigned short)((u + 0x7fffu + ((u >> 16) & 1u)) >> 16);
}
__device__ __forceinline__ unsigned pack2(float a, float b) {
    return (unsigned)f2bf(a) | ((unsigned)f2bf(b) << 16);
}
__device__ __forceinline__ void gload16(const void* g, void* l) {
    __builtin_amdgcn_global_load_lds(
        (const __attribute__((address_space(1))) void*)g,
        (__attribute__((address_space(3))) void*)l, 16, 0, 0);
}

// ---------------------------------------------------------------------------
// node_emb f32 -> bf16 EMB  +  f32 x_all passthrough (fused copy)
// ---------------------------------------------------------------------------
__global__ __launch_bounds__(256)
void conv_emb(const float* __restrict__ ne, unsigned short* __restrict__ emb,
              float* __restrict__ outX, int total4)
{
    const int stride = gridDim.x * blockDim.x;
    for (int i = blockIdx.x * blockDim.x + threadIdx.x; i < total4; i += stride) {
        const float4 v = reinterpret_cast<const float4*>(ne)[i];
        reinterpret_cast<float4*>(outX)[i] = v;
        ushort4 h;
        h.x = f2bf(v.x); h.y = f2bf(v.y); h.z = f2bf(v.z); h.w = f2bf(v.w);
        reinterpret_cast<ushort4*>(emb)[i] = h;
    }
}

// ---------------------------------------------------------------------------
// B-matrix prep: BTm[n][k] (k<1024: rel_W[k>>8][k&255][n], else self_W),
// BTp[n][k] = pre_W[k][n]; both bf16.
// ---------------------------------------------------------------------------
__global__ __launch_bounds__(256)
void build_bt(const float* __restrict__ relW, const float* __restrict__ selfW,
              const float* __restrict__ preW, unsigned short* __restrict__ BTm,
              unsigned short* __restrict__ BTp)
{
    const int idx = blockIdx.x * 256 + threadIdx.x;
    if (idx < 1280 * 256) {
        const int k = idx >> 8, n = idx & 255;
        const float v = (k < 1024)
            ? relW[(size_t)(k >> 8) * 65536 + (size_t)(k & 255) * 256 + n]
            : selfW[(size_t)(k - 1024) * 256 + n];
        BTm[(size_t)n * 1280 + k] = f2bf(v);
    } else {
        const int i2 = idx - 1280 * 256;
        if (i2 < 256 * 256) {
            const int k = i2 >> 8, n = i2 & 255;
            BTp[(size_t)n * 256 + k] = f2bf(preW[(size_t)k * 256 + n]);
        }
    }
}

// ---------------------------------------------------------------------------
// MFMA GEMM: BM=128, BN=256, BK=64, 512 threads (8 waves, 2m x 4n), each
// wave -> 64x64 output (4x4 fragments of 16x16x32 bf16).
// Staging: global_load_lds dwordx4; LDS linear [row][128B], logical granule
// g stored at physical g^(row&7) via source pre-swizzle (read applies same).
// MODE 0: A=EMB bf16, K=256,  C = bf16 gelu(LN1(.+pre_b)) -> XOut
// MODE 1: A=[scaled agg r0..r3 | x] bf16 (5 segment pointers), K=1280,
//         C = f32 LN2(gelu(. + bias + self_b)) -> Cout
// ---------------------------------------------------------------------------
template<int MODE>
__global__ __launch_bounds__(512)
void gemm_mfma(const unsigned short* __restrict__ a0,
               const unsigned short* __restrict__ a1,
               const unsigned short* __restrict__ a2,
               const unsigned short* __restrict__ a3,
               const unsigned short* __restrict__ a4,
               const unsigned short* __restrict__ BT,
               const float* __restrict__ bias0, const float* __restrict__ bias1,
               const float* __restrict__ lng, const float* __restrict__ lnb,
               float* __restrict__ Cout, unsigned short* __restrict__ XOut,
               int M)
{
    constexpr int K    = MODE ? 1280 : 256;
    constexpr int NSEG = MODE ? 5 : 1;

    __shared__ __align__(16) unsigned char smA[128 * 128];   // 16 KB
    __shared__ __align__(16) unsigned char smB[256 * 128];   // 32 KB
    __shared__ float redS[4][128];
    __shared__ float redQ[4][128];

    const int tid = threadIdx.x;
    const int w   = tid >> 6;
    const int l   = tid & 63;
    const int wm  = w >> 2, wn = w & 3;
    const int brow = blockIdx.x * 128;

    const int srow = l >> 3;                 // row within 8-row chunk
    const int sgA  = (l & 7) ^ srow;         // pre-swizzled logical granule

    f32x4 acc[4][4];
#pragma unroll
    for (int mb = 0; mb < 4; ++mb)
#pragma unroll
        for (int nb = 0; nb < 4; ++nb)
            acc[mb][nb] = f32x4{0.f, 0.f, 0.f, 0.f};

    for (int seg = 0; seg < NSEG; ++seg) {
        const unsigned short* Abase =
            (MODE == 0) ? a0
                        : (seg == 0 ? a0 : seg == 1 ? a1 : seg == 2 ? a2
                                         : seg == 3 ? a3 : a4);
#pragma unroll
        for (int kk = 0; kk < 4; ++kk) {
            __syncthreads();     // all waves done reading previous tile
            // ---- A tile: 2 calls/wave, 8 rows each ----
#pragma unroll
            for (int c = 0; c < 2; ++c) {
                const int r0 = (w * 2 + c) * 8;
                int gm = brow + r0 + srow;
                gm = min(gm, M - 1);
                gload16(Abase + ((size_t)gm << 8) + kk * 64 + sgA * 8,
                        smA + (w * 2 + c) * 1024);
            }
            // ---- B tile: 4 calls/wave ----
#pragma unroll
            for (int c = 0; c < 4; ++c) {
                const int bn = (w * 4 + c) * 8 + srow;
                gload16(BT + (size_t)bn * K + (seg * 4 + kk) * 64 + sgA * 8,
                        smB + (w * 4 + c) * 1024);
            }
            __syncthreads();     // vmcnt drained -> tile visible

#pragma unroll
            for (int ks = 0; ks < 2; ++ks) {
                bf16x8 af[4], bf[4];
#pragma unroll
                for (int mb = 0; mb < 4; ++mb) {
                    const int row = wm * 64 + mb * 16 + (l & 15);
                    const int g   = (ks * 4 + (l >> 4)) ^ (row & 7);
                    af[mb] = *reinterpret_cast<const bf16x8*>(smA + row * 128 + g * 16);
                }
#pragma unroll
                for (int nb = 0; nb < 4; ++nb) {
                    const int row = wn * 64 + nb * 16 + (l & 15);
                    const int g   = (ks * 4 + (l >> 4)) ^ (row & 7);
                    bf[nb] = *reinterpret_cast<const bf16x8*>(smB + row * 128 + g * 16);
                }
#pragma unroll
                for (int mb = 0; mb < 4; ++mb)
#pragma unroll
                    for (int nb = 0; nb < 4; ++nb)
                        acc[mb][nb] = __builtin_amdgcn_mfma_f32_16x16x32_bf16(
                            af[mb], bf[nb], acc[mb][nb], 0, 0, 0);
            }
        }
    }

    // ---- epilogue: bias (+gelu for mode1), LN over 256 cols, store ----
    float bb[4], gw[4], bw[4];
#pragma unroll
    for (int nb = 0; nb < 4; ++nb) {
        const int n = wn * 64 + nb * 16 + (l & 15);
        bb[nb] = bias0[n] + (MODE == 1 ? bias1[n] : 0.0f);
        gw[nb] = lng[n];
        bw[nb] = lnb[n];
    }
#pragma unroll
    for (int mb = 0; mb < 4; ++mb)
#pragma unroll
        for (int nb = 0; nb < 4; ++nb)
#pragma unroll
            for (int rg = 0; rg < 4; ++rg) {
                float v = acc[mb][nb][rg] + bb[nb];
                if (MODE == 1) v = gelu_exact(v);
                acc[mb][nb][rg] = v;
            }
#pragma unroll
    for (int mb = 0; mb < 4; ++mb)
#pragma unroll
        for (int rg = 0; rg < 4; ++rg) {
            float s = 0.f, q = 0.f;
#pragma unroll
            for (int nb = 0; nb < 4; ++nb) {
                const float v = acc[mb][nb][rg];
                s += v; q += v * v;
            }
#pragma unroll
            for (int off = 1; off < 16; off <<= 1) {
                s += __shfl_xor(s, off, 64);
                q += __shfl_xor(q, off, 64);
            }
            if ((l & 15) == 0) {
                const int row = wm * 64 + mb * 16 + (l >> 4) * 4 + rg;
                redS[wn][row] = s;
                redQ[wn][row] = q;
            }
        }
    __syncthreads();
    if (tid < 128) {
        const float s = redS[0][tid] + redS[1][tid] + redS[2][tid] + redS[3][tid];
        const float q = redQ[0][tid] + redQ[1][tid] + redQ[2][tid] + redQ[3][tid];
        const float mean = s * (1.0f / 256.0f);
        const float var  = q * (1.0f / 256.0f) - mean * mean;
        redS[0][tid] = mean;
        redQ[0][tid] = rsqrtf(var + 1e-5f);
    }
    __syncthreads();
#pragma unroll
    for (int mb = 0; mb < 4; ++mb)
#pragma unroll
        for (int rg = 0; rg < 4; ++rg) {
            const int row = wm * 64 + mb * 16 + (l >> 4) * 4 + rg;
            if (brow + row >= M) continue;
            const float mu = redS[0][row];
            const float rs = redQ[0][row];
#pragma unroll
            for (int nb = 0; nb < 4; ++nb) {
                const int n = wn * 64 + nb * 16 + (l & 15);
                const float v = (acc[mb][nb][rg] - mu) * rs * gw[nb] + bw[nb];
                if (MODE == 0)
                    XOut[((size_t)(brow + row) << 8) + n] = f2bf(gelu_exact(v));
                else
                    Cout[((size_t)(brow + row) << 8) + n] = v;
            }
        }
}

// ---------------------------------------------------------------------------
// w~[r][k] = sum_j rel_W[r][k][j] * attn_vec[j]   (fp32)
// ---------------------------------------------------------------------------
__global__ __launch_bounds__(256)
void wtilde_kernel(const float* __restrict__ relW, const float* __restrict__ av,
                   float* __restrict__ wt)
{
    __shared__ float avs[256];
    const int r = blockIdx.x, tid = threadIdx.x;
    avs[tid] = av[tid];
    __syncthreads();
    const float* W = relW + (size_t)r * 65536 + (size_t)tid * 256;
    float s = 0.f;
    for (int j = 0; j < 256; j += 4) {
        const float4 w4 = *reinterpret_cast<const float4*>(W + j);
        s += w4.x * avs[j] + w4.y * avs[j + 1] + w4.z * avs[j + 2] + w4.w * avs[j + 3];
    }
    wt[r * 256 + tid] = s;
}

// ---------------------------------------------------------------------------
// y[n][r] = x[n] . w~[r]  — one wave per node.
// ---------------------------------------------------------------------------
__global__ __launch_bounds__(256)
void y_kernel(const unsigned short* __restrict__ XB, const float* __restrict__ wt,
              float* __restrict__ y, int Nn)
{
    const int n = blockIdx.x * 4 + (threadIdx.x >> 6);
    if (n >= Nn) return;
    const int l = threadIdx.x & 63;
    const uint2 d = *reinterpret_cast<const uint2*>(XB + ((size_t)n << 8) + l * 4);
    float xv[4];
    xv[0] = __uint_as_float(d.x << 16);
    xv[1] = __uint_as_float(d.x & 0xffff0000u);
    xv[2] = __uint_as_float(d.y << 16);
    xv[3] = __uint_as_float(d.y & 0xffff0000u);
    float s[4];
#pragma unroll
    for (int r = 0; r < 4; ++r) {
        const float4 w4 = *reinterpret_cast<const float4*>(wt + r * 256 + l * 4);
        s[r] = xv[0] * w4.x + xv[1] * w4.y + xv[2] * w4.z + xv[3] * w4.w;
#pragma unroll
        for (int off = 32; off; off >>= 1) s[r] += __shfl_xor(s[r], off, 64);
    }
    if (l == 0)
        *reinterpret_cast<float4*>(y + (size_t)n * 4) = make_float4(s[0], s[1], s[2], s[3]);
}

// ---------------------------------------------------------------------------
// CSR build (unchanged)
// ---------------------------------------------------------------------------
__global__ __launch_bounds__(256)
void hist_rows(const int* __restrict__ rows, int* __restrict__ counts,
               int RE, int E, int Nn)
{
    const int stride = gridDim.x * blockDim.x;
    for (int e = blockIdx.x * blockDim.x + threadIdx.x; e < RE; e += stride) {
        const int r = e / E;
        atomicAdd(&counts[r * Nn + rows[e]], 1);
    }
}

__global__ __launch_bounds__(256)
void scan_blocks(const int* __restrict__ counts, int* __restrict__ offs,
                 int* __restrict__ bsums, int n)
{
    __shared__ int sh[256];
    const int t = threadIdx.x;
    const int base = blockIdx.x * 1024 + t * 4;
    int v[4], s = 0;
#pragma unroll
    for (int j = 0; j < 4; ++j) {
        v[j] = (base + j < n) ? counts[base + j] : 0;
        s += v[j];
    }
    sh[t] = s;
    __syncthreads();
    for (int off = 1; off < 256; off <<= 1) {
        const int x = (t >= off) ? sh[t - off] : 0;
        __syncthreads();
        sh[t] += x;
        __syncthreads();
    }
    int run = sh[t] - s;
    if (t == 255) bsums[blockIdx.x] = sh[255];
#pragma unroll
    for (int j = 0; j < 4; ++j) {
        if (base + j < n) offs[base + j] = run;
        run += v[j];
    }
}

__global__ __launch_bounds__(256)
void scan_bsums(int* __restrict__ bsums, int nblk)
{
    __shared__ int sh[256];
    const int t = threadIdx.x;
    const int v = (t < nblk) ? bsums[t] : 0;
    sh[t] = v;
    __syncthreads();
    for (int off = 1; off < 256; off <<= 1) {
        const int x = (t >= off) ? sh[t - off] : 0;
        __syncthreads();
        sh[t] += x;
        __syncthreads();
    }
    if (t < nblk) bsums[t] = sh[t] - v;
}

__global__ __launch_bounds__(256)
void scan_add(int* __restrict__ offs, int* __restrict__ cursor,
              const int* __restrict__ bsums, int n)
{
    const int i = blockIdx.x * 256 + threadIdx.x;
    if (i >= n) return;
    const int v = offs[i] + bsums[i >> 10];
    offs[i]   = v;
    cursor[i] = v;
}

__global__ __launch_bounds__(256)
void scatter_edges(const int* __restrict__ rows, const int* __restrict__ cols,
                   const float* __restrict__ vals, int* __restrict__ cursor,
                   u64* __restrict__ edata, int RE, int E, int Nn)
{
    const int stride = gridDim.x * blockDim.x;
    for (int e = blockIdx.x * blockDim.x + threadIdx.x; e < RE; e += stride) {
        const int r   = e / E;
        const int pos = atomicAdd(&cursor[r * Nn + rows[e]], 1);
        edata[pos] = ((u64)__float_as_uint(vals[e]) << 32) | (unsigned)cols[e];
    }
}

// ---------------------------------------------------------------------------
// Edge-wise scores: score[n][r] = sum val * y[col][r]; sentinel if deg==0.
// One thread per (r,n).
// ---------------------------------------------------------------------------
__global__ __launch_bounds__(256)
void score_csr(const int* __restrict__ offs, const u64* __restrict__ edata,
               const float* __restrict__ y, float* __restrict__ scores,
               int Nn, int RE)
{
    const int wid = blockIdx.x * 256 + threadIdx.x;
    const int RN  = Nn << 2;
    if (wid >= RN) return;
    const int r = wid / Nn;
    const int n = wid - r * Nn;
    const int start = offs[wid];
    const int end   = (wid + 1 < RN) ? offs[wid + 1] : RE;

    float s = 0.f;
    int j = start;
    for (; j + 3 < end; j += 4) {
        u64 e[4];
        float yv[4], vv[4];
#pragma unroll
        for (int q = 0; q < 4; ++q) e[q] = edata[j + q];
#pragma unroll
        for (int q = 0; q < 4; ++q) {
            vv[q] = __uint_as_float((unsigned)(e[q] >> 32));
            yv[q] = y[((size_t)(unsigned)(e[q] & 0xffffffffu)) * 4 + r];
        }
#pragma unroll
        for (int q = 0; q < 4; ++q) s = fmaf(vv[q], yv[q], s);
    }
    for (; j < end; ++j) {
        const u64 e0 = edata[j];
        s = fmaf(__uint_as_float((unsigned)(e0 >> 32)),
                 y[((size_t)(unsigned)(e0 & 0xffffffffu)) * 4 + r], s);
    }
    scores[(size_t)n * 4 + r] = (end > start) ? s : -1e30f;
}

// ---------------------------------------------------------------------------
// Per-node masked softmax over 4 relation scores.
// ---------------------------------------------------------------------------
__global__ __launch_bounds__(256)
void softmax4(const float* __restrict__ scores, float* __restrict__ attn, int Nn)
{
    const int n = blockIdx.x * 256 + threadIdx.x;
    if (n >= Nn) return;
    const float4 s4 = *reinterpret_cast<const float4*>(scores + (size_t)n * 4);
    float s[4] = { s4.x, s4.y, s4.z, s4.w };
    float mx = -3.0e38f;
#pragma unroll
    for (int r = 0; r < 4; ++r) mx = fmaxf(mx, s[r]);
    float ex[4], es = 0.f;
#pragma unroll
    for (int r = 0; r < 4; ++r) { ex[r] = expf(s[r] - mx); es += ex[r]; }
    const float inv = 1.0f / es;
    float4 o;
    o.x = (s[0] > -1e29f) ? ex[0] * inv : 0.0f;
    o.y = (s[1] > -1e29f) ? ex[1] * inv : 0.0f;
    o.z = (s[2] > -1e29f) ? ex[2] * inv : 0.0f;
    o.w = (s[3] > -1e29f) ? ex[3] * inv : 0.0f;
    *reinterpret_cast<float4*>(attn + (size_t)n * 4) = o;
}

// ---------------------------------------------------------------------------
// Aggregation: one wave per (r,n). bf16 gather, f32 acc, attn-scaled bf16
// store (scale known because scores were computed edge-wise beforehand).
// ---------------------------------------------------------------------------
__global__ __launch_bounds__(256)
void agg_csr(const int* __restrict__ offs, const u64* __restrict__ edata,
             const unsigned short* __restrict__ x, const float* __restrict__ attn,
             unsigned short* __restrict__ agg, int Nn, int RE)
{
    const int wid  = (blockIdx.x << 2) + (threadIdx.x >> 6);
    const int lane = threadIdx.x & 63;
    const int RN   = Nn << 2;
    if (wid >= RN) return;
    const int r = wid / Nn;
    const int n = wid - r * Nn;

    const int start = offs[wid];
    const int end   = (wid + 1 < RN) ? offs[wid + 1] : RE;

    float ax = 0.f, ay = 0.f, az = 0.f, aw = 0.f;
    int j = start;
    for (; j + 3 < end; j += 4) {
        u64 e[4];
        uint2 d[4];
        float v[4];
#pragma unroll
        for (int q = 0; q < 4; ++q) e[q] = edata[j + q];
#pragma unroll
        for (int q = 0; q < 4; ++q) {
            const int c = (int)(e[q] & 0xffffffffu);
            v[q] = __uint_as_float((unsigned)(e[q] >> 32));
            d[q] = *reinterpret_cast<const uint2*>(x + ((size_t)c << 8) + lane * 4);
        }
#pragma unroll
        for (int q = 0; q < 4; ++q) {
            ax = fmaf(v[q], __uint_as_float(d[q].x << 16),         ax);
            ay = fmaf(v[q], __uint_as_float(d[q].x & 0xffff0000u), ay);
            az = fmaf(v[q], __uint_as_float(d[q].y << 16),         az);
            aw = fmaf(v[q], __uint_as_float(d[q].y & 0xffff0000u), aw);
        }
    }
    for (; j < end; ++j) {
        const u64 e0 = edata[j];
        const int   c0 = (int)(e0 & 0xffffffffu);
        const float v0 = __uint_as_float((unsigned)(e0 >> 32));
        const uint2 d0 = *reinterpret_cast<const uint2*>(x + ((size_t)c0 << 8) + lane * 4);
        ax = fmaf(v0, __uint_as_float(d0.x << 16),         ax);
        ay = fmaf(v0, __uint_as_float(d0.x & 0xffff0000u), ay);
        az = fmaf(v0, __uint_as_float(d0.y << 16),         az);
        aw = fmaf(v0, __uint_as_float(d0.y & 0xffff0000u), aw);
    }

    const float sc = attn[(size_t)n * 4 + r];
    uint2 st;
    st.x = pack2(sc * ax, sc * ay);
    st.y = pack2(sc * az, sc * aw);
    *reinterpret_cast<uint2*>(agg + ((size_t)wid << 8) + lane * 4) = st;
}

// ---------------------------------------------------------------------------
extern "C" void kernel_launch(void* const* d_in, const int* in_sizes, int n_in,
                              void* d_out, int out_size, void* d_ws, size_t ws_size,
                              hipStream_t stream)
{
    const int*   rows     = (const int*)d_in[0];
    const int*   cols     = (const int*)d_in[1];
    const float* vals     = (const float*)d_in[2];
    const float* node_emb = (const float*)d_in[3];
    const float* pre_W    = (const float*)d_in[4];
    const float* pre_b    = (const float*)d_in[5];
    const float* ln1_g    = (const float*)d_in[6];
    const float* ln1_b    = (const float*)d_in[7];
    const float* rel_W    = (const float*)d_in[8];
    const float* attn_vec = (const float*)d_in[9];
    const float* self_W   = (const float*)d_in[10];
    const float* self_b   = (const float*)d_in[11];
    const float* bias     = (const float*)d_in[12];
    const float* ln2_g    = (const float*)d_in[13];
    const float* ln2_b    = (const float*)d_in[14];

    const int Dd = 256;
    const int R  = in_sizes[8] / (Dd * Dd);   // 4
    const int N  = in_sizes[3] / Dd;          // 50000
    const int E  = in_sizes[0] / R;           // 800000
    const int RE = R * E;
    const int RN = R * N;

    float* out  = (float*)d_out;
    float* outF = out;                              // final  [N][256] f32
    float* outA = out + (size_t)N * Dd;             // attn   [N][4]   f32
    float* outX = outA + (size_t)N * R;             // x_all  [N][256] f32

    char* wp = (char*)d_ws;
    auto alloc = [&](size_t bytes) {
        char* p = wp;
        wp += (bytes + 255) & ~(size_t)255;
        return p;
    };
    unsigned short* AGGS = (unsigned short*)alloc((size_t)RN * Dd * 2);   // 102.4 MB
    unsigned short* XB   = (unsigned short*)alloc((size_t)N * Dd * 2);    //  25.6 MB
    unsigned short* EMB  = (unsigned short*)alloc((size_t)N * Dd * 2);    //  25.6 MB
    unsigned short* BTm  = (unsigned short*)alloc((size_t)Dd * 1280 * 2); // 655 KB
    unsigned short* BTp  = (unsigned short*)alloc((size_t)Dd * Dd * 2);   // 131 KB
    float* WT  = (float*)alloc((size_t)R * Dd * 4);
    float* Y   = (float*)alloc((size_t)N * R * 4);
    float* SC  = (float*)alloc((size_t)N * R * 4);
    int* counts = (int*)alloc((size_t)RN * 4);
    int* offs   = (int*)alloc((size_t)RN * 4);
    int* cursor = (int*)alloc((size_t)RN * 4);
    int* bsums  = (int*)alloc(1024);
    u64* edata  = (u64*)alloc((size_t)RE * 8);                            // 25.6 MB

    const int gblocks = (N + 127) / 128;            // 391
    const int nblk    = (RN + 1023) / 1024;         // 196

    // 1. B-matrix prep + emb conversion (+x_all passthrough)
    build_bt<<<(1280 * 256 + 256 * 256 + 255) / 256, 256, 0, stream>>>(
        rel_W, self_W, pre_W, BTm, BTp);
    conv_emb<<<2048, 256, 0, stream>>>(node_emb, EMB, outX, N * Dd / 4);

    // 2. pre-encoder -> X bf16
    gemm_mfma<0><<<gblocks, 512, 0, stream>>>(EMB, nullptr, nullptr, nullptr, nullptr,
                                              BTp, pre_b, nullptr, ln1_g, ln1_b,
                                              nullptr, XB, N);
    // 3. w~ and y
    wtilde_kernel<<<R, 256, 0, stream>>>(rel_W, attn_vec, WT);
    y_kernel<<<(N + 3) / 4, 256, 0, stream>>>(XB, WT, Y, N);

    // 4. CSR build
    hipMemsetAsync(counts, 0, (size_t)RN * sizeof(int), stream);
    hist_rows<<<2048, 256, 0, stream>>>(rows, counts, RE, E, N);
    scan_blocks<<<nblk, 256, 0, stream>>>(counts, offs, bsums, RN);
    scan_bsums<<<1, 256, 0, stream>>>(bsums, nblk);
    scan_add<<<(RN + 255) / 256, 256, 0, stream>>>(offs, cursor, bsums, RN);
    scatter_edges<<<2048, 256, 0, stream>>>(rows, cols, vals, cursor, edata, RE, E, N);

    // 5. edge-wise scores -> masked softmax -> attn (outA)
    score_csr<<<(RN + 255) / 256, 256, 0, stream>>>(offs, edata, Y, SC, N, RE);
    softmax4<<<(N + 255) / 256, 256, 0, stream>>>(SC, outA, N);

    // 6. aggregation with fused attn scaling
    agg_csr<<<(RN + 3) / 4, 256, 0, stream>>>(offs, edata, XB, outA, AGGS, N, RE);

    // 7. mega-GEMM -> final (outF)
    gemm_mfma<1><<<gblocks, 512, 0, stream>>>(AGGS, AGGS + (size_t)N * Dd,
                                              AGGS + (size_t)2 * N * Dd,
                                              AGGS + (size_t)3 * N * Dd, XB,
                                              BTm, bias, self_b, ln2_g, ln2_b,
                                              outF, nullptr, N);
}

// Round 5
// 801.134 us; speedup vs baseline: 14.3424x; 1.0152x over previous
//
#include <hip/hip_runtime.h>
#include <math.h>

// ---------------------------------------------------------------------------
// LearnableWeightedRGCN — round 4.
// Key changes vs R3:
//  * attn-scaling moved OUT of the mega-GEMM: scores computed edge-wise from
//    y[n][r]=x[n]·w~[r] BEFORE aggregation; agg_csr stores attn-scaled bf16.
//    -> GEMM needs one accumulator (64 AGPR, was 128) -> 3x occupancy.
//  * GEMM restructured: 128x256 tile, 8 waves, BK=64, global_load_lds(16B)
//    staging with XOR-(row&7) source pre-swizzle, 2-barrier loop (m97-style).
//  * conv_emb: node_emb -> bf16 A-matrix + f32 x_all output in one pass.
// ---------------------------------------------------------------------------

typedef __attribute__((ext_vector_type(8))) short bf16x8;
typedef __attribute__((ext_vector_type(4))) float f32x4;
typedef unsigned long long u64;

__device__ __forceinline__ float gelu_exact(float v) {
    return 0.5f * v * (1.0f + erff(v * 0.70710678118654752f));
}
__device__ __forceinline__ unsigned short f2bf(float f) {   // RNE
    unsigned u = __float_as_uint(f);
    return (unsigned short)((u + 0x7fffu + ((u >> 16) & 1u)) >> 16);
}
__device__ __forceinline__ unsigned pack2(float a, float b) {
    return (unsigned)f2bf(a) | ((unsigned)f2bf(b) << 16);
}
__device__ __forceinline__ void gload16(const void* g, void* l) {
    __builtin_amdgcn_global_load_lds(
        (const __attribute__((address_space(1))) void*)g,
        (__attribute__((address_space(3))) void*)l, 16, 0, 0);
}

// ---------------------------------------------------------------------------
// node_emb f32 -> bf16 EMB  +  f32 x_all passthrough (fused copy)
// ---------------------------------------------------------------------------
__global__ __launch_bounds__(256)
void conv_emb(const float* __restrict__ ne, unsigned short* __restrict__ emb,
              float* __restrict__ outX, int total4)
{
    const int stride = gridDim.x * blockDim.x;
    for (int i = blockIdx.x * blockDim.x + threadIdx.x; i < total4; i += stride) {
        const float4 v = reinterpret_cast<const float4*>(ne)[i];
        reinterpret_cast<float4*>(outX)[i] = v;
        ushort4 h;
        h.x = f2bf(v.x); h.y = f2bf(v.y); h.z = f2bf(v.z); h.w = f2bf(v.w);
        reinterpret_cast<ushort4*>(emb)[i] = h;
    }
}

// ---------------------------------------------------------------------------
// B-matrix prep: BTm[n][k] (k<1024: rel_W[k>>8][k&255][n], else self_W),
// BTp[n][k] = pre_W[k][n]; both bf16.
// ---------------------------------------------------------------------------
__global__ __launch_bounds__(256)
void build_bt(const float* __restrict__ relW, const float* __restrict__ selfW,
              const float* __restrict__ preW, unsigned short* __restrict__ BTm,
              unsigned short* __restrict__ BTp)
{
    const int idx = blockIdx.x * 256 + threadIdx.x;
    if (idx < 1280 * 256) {
        const int k = idx >> 8, n = idx & 255;
        const float v = (k < 1024)
            ? relW[(size_t)(k >> 8) * 65536 + (size_t)(k & 255) * 256 + n]
            : selfW[(size_t)(k - 1024) * 256 + n];
        BTm[(size_t)n * 1280 + k] = f2bf(v);
    } else {
        const int i2 = idx - 1280 * 256;
        if (i2 < 256 * 256) {
            const int k = i2 >> 8, n = i2 & 255;
            BTp[(size_t)n * 256 + k] = f2bf(preW[(size_t)k * 256 + n]);
        }
    }
}

// ---------------------------------------------------------------------------
// MFMA GEMM: BM=128, BN=256, BK=64, 512 threads (8 waves, 2m x 4n), each
// wave -> 64x64 output (4x4 fragments of 16x16x32 bf16).
// Staging: global_load_lds dwordx4; LDS linear [row][128B], logical granule
// g stored at physical g^(row&7) via source pre-swizzle (read applies same).
// MODE 0: A=EMB bf16, K=256,  C = bf16 gelu(LN1(.+pre_b)) -> XOut
// MODE 1: A=[scaled agg r0..r3 | x] bf16 (5 segment pointers), K=1280,
//         C = f32 LN2(gelu(. + bias + self_b)) -> Cout
// ---------------------------------------------------------------------------
template<int MODE>
__global__ __launch_bounds__(512)
void gemm_mfma(const unsigned short* __restrict__ a0,
               const unsigned short* __restrict__ a1,
               const unsigned short* __restrict__ a2,
               const unsigned short* __restrict__ a3,
               const unsigned short* __restrict__ a4,
               const unsigned short* __restrict__ BT,
               const float* __restrict__ bias0, const float* __restrict__ bias1,
               const float* __restrict__ lng, const float* __restrict__ lnb,
               float* __restrict__ Cout, unsigned short* __restrict__ XOut,
               int M)
{
    constexpr int K    = MODE ? 1280 : 256;
    constexpr int NSEG = MODE ? 5 : 1;

    __shared__ __align__(16) unsigned char smA[128 * 128];   // 16 KB
    __shared__ __align__(16) unsigned char smB[256 * 128];   // 32 KB
    __shared__ float redS[4][128];
    __shared__ float redQ[4][128];

    const int tid = threadIdx.x;
    const int w   = tid >> 6;
    const int l   = tid & 63;
    const int wm  = w >> 2, wn = w & 3;
    const int brow = blockIdx.x * 128;

    const int srow = l >> 3;                 // row within 8-row chunk
    const int sgA  = (l & 7) ^ srow;         // pre-swizzled logical granule

    f32x4 acc[4][4];
#pragma unroll
    for (int mb = 0; mb < 4; ++mb)
#pragma unroll
        for (int nb = 0; nb < 4; ++nb)
            acc[mb][nb] = f32x4{0.f, 0.f, 0.f, 0.f};

    for (int seg = 0; seg < NSEG; ++seg) {
        const unsigned short* Abase =
            (MODE == 0) ? a0
                        : (seg == 0 ? a0 : seg == 1 ? a1 : seg == 2 ? a2
                                         : seg == 3 ? a3 : a4);
#pragma unroll
        for (int kk = 0; kk < 4; ++kk) {
            __syncthreads();     // all waves done reading previous tile
            // ---- A tile: 2 calls/wave, 8 rows each ----
#pragma unroll
            for (int c = 0; c < 2; ++c) {
                const int r0 = (w * 2 + c) * 8;
                int gm = brow + r0 + srow;
                gm = min(gm, M - 1);
                gload16(Abase + ((size_t)gm << 8) + kk * 64 + sgA * 8,
                        smA + (w * 2 + c) * 1024);
            }
            // ---- B tile: 4 calls/wave ----
#pragma unroll
            for (int c = 0; c < 4; ++c) {
                const int bn = (w * 4 + c) * 8 + srow;
                gload16(BT + (size_t)bn * K + (seg * 4 + kk) * 64 + sgA * 8,
                        smB + (w * 4 + c) * 1024);
            }
            __syncthreads();     // vmcnt drained -> tile visible

#pragma unroll
            for (int ks = 0; ks < 2; ++ks) {
                bf16x8 af[4], bf[4];
#pragma unroll
                for (int mb = 0; mb < 4; ++mb) {
                    const int row = wm * 64 + mb * 16 + (l & 15);
                    const int g   = (ks * 4 + (l >> 4)) ^ (row & 7);
                    af[mb] = *reinterpret_cast<const bf16x8*>(smA + row * 128 + g * 16);
                }
#pragma unroll
                for (int nb = 0; nb < 4; ++nb) {
                    const int row = wn * 64 + nb * 16 + (l & 15);
                    const int g   = (ks * 4 + (l >> 4)) ^ (row & 7);
                    bf[nb] = *reinterpret_cast<const bf16x8*>(smB + row * 128 + g * 16);
                }
#pragma unroll
                for (int mb = 0; mb < 4; ++mb)
#pragma unroll
                    for (int nb = 0; nb < 4; ++nb)
                        acc[mb][nb] = __builtin_amdgcn_mfma_f32_16x16x32_bf16(
                            af[mb], bf[nb], acc[mb][nb], 0, 0, 0);
            }
        }
    }

    // ---- epilogue: bias (+gelu for mode1), LN over 256 cols, store ----
    float bb[4], gw[4], bw[4];
#pragma unroll
    for (int nb = 0; nb < 4; ++nb) {
        const int n = wn * 64 + nb * 16 + (l & 15);
        bb[nb] = bias0[n] + (MODE == 1 ? bias1[n] : 0.0f);
        gw[nb] = lng[n];
        bw[nb] = lnb[n];
    }
#pragma unroll
    for (int mb = 0; mb < 4; ++mb)
#pragma unroll
        for (int nb = 0; nb < 4; ++nb)
#pragma unroll
            for (int rg = 0; rg < 4; ++rg) {
                float v = acc[mb][nb][rg] + bb[nb];
                if (MODE == 1) v = gelu_exact(v);
                acc[mb][nb][rg] = v;
            }
#pragma unroll
    for (int mb = 0; mb < 4; ++mb)
#pragma unroll
        for (int rg = 0; rg < 4; ++rg) {
            float s = 0.f, q = 0.f;
#pragma unroll
            for (int nb = 0; nb < 4; ++nb) {
                const float v = acc[mb][nb][rg];
                s += v; q += v * v;
            }
#pragma unroll
            for (int off = 1; off < 16; off <<= 1) {
                s += __shfl_xor(s, off, 64);
                q += __shfl_xor(q, off, 64);
            }
            if ((l & 15) == 0) {
                const int row = wm * 64 + mb * 16 + (l >> 4) * 4 + rg;
                redS[wn][row] = s;
                redQ[wn][row] = q;
            }
        }
    __syncthreads();
    if (tid < 128) {
        const float s = redS[0][tid] + redS[1][tid] + redS[2][tid] + redS[3][tid];
        const float q = redQ[0][tid] + redQ[1][tid] + redQ[2][tid] + redQ[3][tid];
        const float mean = s * (1.0f / 256.0f);
        const float var  = q * (1.0f / 256.0f) - mean * mean;
        redS[0][tid] = mean;
        redQ[0][tid] = rsqrtf(var + 1e-5f);
    }
    __syncthreads();
#pragma unroll
    for (int mb = 0; mb < 4; ++mb)
#pragma unroll
        for (int rg = 0; rg < 4; ++rg) {
            const int row = wm * 64 + mb * 16 + (l >> 4) * 4 + rg;
            if (brow + row >= M) continue;
            const float mu = redS[0][row];
            const float rs = redQ[0][row];
#pragma unroll
            for (int nb = 0; nb < 4; ++nb) {
                const int n = wn * 64 + nb * 16 + (l & 15);
                const float v = (acc[mb][nb][rg] - mu) * rs * gw[nb] + bw[nb];
                if (MODE == 0)
                    XOut[((size_t)(brow + row) << 8) + n] = f2bf(gelu_exact(v));
                else
                    Cout[((size_t)(brow + row) << 8) + n] = v;
            }
        }
}

// ---------------------------------------------------------------------------
// w~[r][k] = sum_j rel_W[r][k][j] * attn_vec[j]   (fp32)
// ---------------------------------------------------------------------------
__global__ __launch_bounds__(256)
void wtilde_kernel(const float* __restrict__ relW, const float* __restrict__ av,
                   float* __restrict__ wt)
{
    __shared__ float avs[256];
    const int r = blockIdx.x, tid = threadIdx.x;
    avs[tid] = av[tid];
    __syncthreads();
    const float* W = relW + (size_t)r * 65536 + (size_t)tid * 256;
    float s = 0.f;
    for (int j = 0; j < 256; j += 4) {
        const float4 w4 = *reinterpret_cast<const float4*>(W + j);
        s += w4.x * avs[j] + w4.y * avs[j + 1] + w4.z * avs[j + 2] + w4.w * avs[j + 3];
    }
    wt[r * 256 + tid] = s;
}

// ---------------------------------------------------------------------------
// y[n][r] = x[n] . w~[r]  — one wave per node.
// ---------------------------------------------------------------------------
__global__ __launch_bounds__(256)
void y_kernel(const unsigned short* __restrict__ XB, const float* __restrict__ wt,
              float* __restrict__ y, int Nn)
{
    const int n = blockIdx.x * 4 + (threadIdx.x >> 6);
    if (n >= Nn) return;
    const int l = threadIdx.x & 63;
    const uint2 d = *reinterpret_cast<const uint2*>(XB + ((size_t)n << 8) + l * 4);
    float xv[4];
    xv[0] = __uint_as_float(d.x << 16);
    xv[1] = __uint_as_float(d.x & 0xffff0000u);
    xv[2] = __uint_as_float(d.y << 16);
    xv[3] = __uint_as_float(d.y & 0xffff0000u);
    float s[4];
#pragma unroll
    for (int r = 0; r < 4; ++r) {
        const float4 w4 = *reinterpret_cast<const float4*>(wt + r * 256 + l * 4);
        s[r] = xv[0] * w4.x + xv[1] * w4.y + xv[2] * w4.z + xv[3] * w4.w;
#pragma unroll
        for (int off = 32; off; off >>= 1) s[r] += __shfl_xor(s[r], off, 64);
    }
    if (l == 0)
        *reinterpret_cast<float4*>(y + (size_t)n * 4) = make_float4(s[0], s[1], s[2], s[3]);
}

// ---------------------------------------------------------------------------
// CSR build (unchanged)
// ---------------------------------------------------------------------------
__global__ __launch_bounds__(256)
void hist_rows(const int* __restrict__ rows, int* __restrict__ counts,
               int RE, int E, int Nn)
{
    const int stride = gridDim.x * blockDim.x;
    for (int e = blockIdx.x * blockDim.x + threadIdx.x; e < RE; e += stride) {
        const int r = e / E;
        atomicAdd(&counts[r * Nn + rows[e]], 1);
    }
}

__global__ __launch_bounds__(256)
void scan_blocks(const int* __restrict__ counts, int* __restrict__ offs,
                 int* __restrict__ bsums, int n)
{
    __shared__ int sh[256];
    const int t = threadIdx.x;
    const int base = blockIdx.x * 1024 + t * 4;
    int v[4], s = 0;
#pragma unroll
    for (int j = 0; j < 4; ++j) {
        v[j] = (base + j < n) ? counts[base + j] : 0;
        s += v[j];
    }
    sh[t] = s;
    __syncthreads();
    for (int off = 1; off < 256; off <<= 1) {
        const int x = (t >= off) ? sh[t - off] : 0;
        __syncthreads();
        sh[t] += x;
        __syncthreads();
    }
    int run = sh[t] - s;
    if (t == 255) bsums[blockIdx.x] = sh[255];
#pragma unroll
    for (int j = 0; j < 4; ++j) {
        if (base + j < n) offs[base + j] = run;
        run += v[j];
    }
}

__global__ __launch_bounds__(256)
void scan_bsums(int* __restrict__ bsums, int nblk)
{
    __shared__ int sh[256];
    const int t = threadIdx.x;
    const int v = (t < nblk) ? bsums[t] : 0;
    sh[t] = v;
    __syncthreads();
    for (int off = 1; off < 256; off <<= 1) {
        const int x = (t >= off) ? sh[t - off] : 0;
        __syncthreads();
        sh[t] += x;
        __syncthreads();
    }
    if (t < nblk) bsums[t] = sh[t] - v;
}

__global__ __launch_bounds__(256)
void scan_add(int* __restrict__ offs, int* __restrict__ cursor,
              const int* __restrict__ bsums, int n)
{
    const int i = blockIdx.x * 256 + threadIdx.x;
    if (i >= n) return;
    const int v = offs[i] + bsums[i >> 10];
    offs[i]   = v;
    cursor[i] = v;
}

__global__ __launch_bounds__(256)
void scatter_edges(const int* __restrict__ rows, const int* __restrict__ cols,
                   const float* __restrict__ vals, int* __restrict__ cursor,
                   u64* __restrict__ edata, int RE, int E, int Nn)
{
    const int stride = gridDim.x * blockDim.x;
    for (int e = blockIdx.x * blockDim.x + threadIdx.x; e < RE; e += stride) {
        const int r   = e / E;
        const int pos = atomicAdd(&cursor[r * Nn + rows[e]], 1);
        edata[pos] = ((u64)__float_as_uint(vals[e]) << 32) | (unsigned)cols[e];
    }
}

// ---------------------------------------------------------------------------
// Edge-wise scores: score[n][r] = sum val * y[col][r]; sentinel if deg==0.
// One thread per (r,n).
// ---------------------------------------------------------------------------
__global__ __launch_bounds__(256)
void score_csr(const int* __restrict__ offs, const u64* __restrict__ edata,
               const float* __restrict__ y, float* __restrict__ scores,
               int Nn, int RE)
{
    const int wid = blockIdx.x * 256 + threadIdx.x;
    const int RN  = Nn << 2;
    if (wid >= RN) return;
    const int r = wid / Nn;
    const int n = wid - r * Nn;
    const int start = offs[wid];
    const int end   = (wid + 1 < RN) ? offs[wid + 1] : RE;

    float s = 0.f;
    int j = start;
    for (; j + 3 < end; j += 4) {
        u64 e[4];
        float yv[4], vv[4];
#pragma unroll
        for (int q = 0; q < 4; ++q) e[q] = edata[j + q];
#pragma unroll
        for (int q = 0; q < 4; ++q) {
            vv[q] = __uint_as_float((unsigned)(e[q] >> 32));
            yv[q] = y[((size_t)(unsigned)(e[q] & 0xffffffffu)) * 4 + r];
        }
#pragma unroll
        for (int q = 0; q < 4; ++q) s = fmaf(vv[q], yv[q], s);
    }
    for (; j < end; ++j) {
        const u64 e0 = edata[j];
        s = fmaf(__uint_as_float((unsigned)(e0 >> 32)),
                 y[((size_t)(unsigned)(e0 & 0xffffffffu)) * 4 + r], s);
    }
    scores[(size_t)n * 4 + r] = (end > start) ? s : -1e30f;
}

// ---------------------------------------------------------------------------
// Per-node masked softmax over 4 relation scores.
// ---------------------------------------------------------------------------
__global__ __launch_bounds__(256)
void softmax4(const float* __restrict__ scores, float* __restrict__ attn, int Nn)
{
    const int n = blockIdx.x * 256 + threadIdx.x;
    if (n >= Nn) return;
    const float4 s4 = *reinterpret_cast<const float4*>(scores + (size_t)n * 4);
    float s[4] = { s4.x, s4.y, s4.z, s4.w };
    float mx = -3.0e38f;
#pragma unroll
    for (int r = 0; r < 4; ++r) mx = fmaxf(mx, s[r]);
    float ex[4], es = 0.f;
#pragma unroll
    for (int r = 0; r < 4; ++r) { ex[r] = expf(s[r] - mx); es += ex[r]; }
    const float inv = 1.0f / es;
    float4 o;
    o.x = (s[0] > -1e29f) ? ex[0] * inv : 0.0f;
    o.y = (s[1] > -1e29f) ? ex[1] * inv : 0.0f;
    o.z = (s[2] > -1e29f) ? ex[2] * inv : 0.0f;
    o.w = (s[3] > -1e29f) ? ex[3] * inv : 0.0f;
    *reinterpret_cast<float4*>(attn + (size_t)n * 4) = o;
}

// ---------------------------------------------------------------------------
// Aggregation: one wave per (r,n). bf16 gather, f32 acc, attn-scaled bf16
// store (scale known because scores were computed edge-wise beforehand).
// ---------------------------------------------------------------------------
__global__ __launch_bounds__(256)
void agg_csr(const int* __restrict__ offs, const u64* __restrict__ edata,
             const unsigned short* __restrict__ x, const float* __restrict__ attn,
             unsigned short* __restrict__ agg, int Nn, int RE)
{
    const int wid  = (blockIdx.x << 2) + (threadIdx.x >> 6);
    const int lane = threadIdx.x & 63;
    const int RN   = Nn << 2;
    if (wid >= RN) return;
    const int r = wid / Nn;
    const int n = wid - r * Nn;

    const int start = offs[wid];
    const int end   = (wid + 1 < RN) ? offs[wid + 1] : RE;

    float ax = 0.f, ay = 0.f, az = 0.f, aw = 0.f;
    int j = start;
    for (; j + 3 < end; j += 4) {
        u64 e[4];
        uint2 d[4];
        float v[4];
#pragma unroll
        for (int q = 0; q < 4; ++q) e[q] = edata[j + q];
#pragma unroll
        for (int q = 0; q < 4; ++q) {
            const int c = (int)(e[q] & 0xffffffffu);
            v[q] = __uint_as_float((unsigned)(e[q] >> 32));
            d[q] = *reinterpret_cast<const uint2*>(x + ((size_t)c << 8) + lane * 4);
        }
#pragma unroll
        for (int q = 0; q < 4; ++q) {
            ax = fmaf(v[q], __uint_as_float(d[q].x << 16),         ax);
            ay = fmaf(v[q], __uint_as_float(d[q].x & 0xffff0000u), ay);
            az = fmaf(v[q], __uint_as_float(d[q].y << 16),         az);
            aw = fmaf(v[q], __uint_as_float(d[q].y & 0xffff0000u), aw);
        }
    }
    for (; j < end; ++j) {
        const u64 e0 = edata[j];
        const int   c0 = (int)(e0 & 0xffffffffu);
        const float v0 = __uint_as_float((unsigned)(e0 >> 32));
        const uint2 d0 = *reinterpret_cast<const uint2*>(x + ((size_t)c0 << 8) + lane * 4);
        ax = fmaf(v0, __uint_as_float(d0.x << 16),         ax);
        ay = fmaf(v0, __uint_as_float(d0.x & 0xffff0000u), ay);
        az = fmaf(v0, __uint_as_float(d0.y << 16),         az);
        aw = fmaf(v0, __uint_as_float(d0.y & 0xffff0000u), aw);
    }

    const float sc = attn[(size_t)n * 4 + r];
    uint2 st;
    st.x = pack2(sc * ax, sc * ay);
    st.y = pack2(sc * az, sc * aw);
    *reinterpret_cast<uint2*>(agg + ((size_t)wid << 8) + lane * 4) = st;
}

// ---------------------------------------------------------------------------
extern "C" void kernel_launch(void* const* d_in, const int* in_sizes, int n_in,
                              void* d_out, int out_size, void* d_ws, size_t ws_size,
                              hipStream_t stream)
{
    const int*   rows     = (const int*)d_in[0];
    const int*   cols     = (const int*)d_in[1];
    const float* vals     = (const float*)d_in[2];
    const float* node_emb = (const float*)d_in[3];
    const float* pre_W    = (const float*)d_in[4];
    const float* pre_b    = (const float*)d_in[5];
    const float* ln1_g    = (const float*)d_in[6];
    const float* ln1_b    = (const float*)d_in[7];
    const float* rel_W    = (const float*)d_in[8];
    const float* attn_vec = (const float*)d_in[9];
    const float* self_W   = (const float*)d_in[10];
    const float* self_b   = (const float*)d_in[11];
    const float* bias     = (const float*)d_in[12];
    const float* ln2_g    = (const float*)d_in[13];
    const float* ln2_b    = (const float*)d_in[14];

    const int Dd = 256;
    const int R  = in_sizes[8] / (Dd * Dd);   // 4
    const int N  = in_sizes[3] / Dd;          // 50000
    const int E  = in_sizes[0] / R;           // 800000
    const int RE = R * E;
    const int RN = R * N;

    float* out  = (float*)d_out;
    float* outF = out;                              // final  [N][256] f32
    float* outA = out + (size_t)N * Dd;             // attn   [N][4]   f32
    float* outX = outA + (size_t)N * R;             // x_all  [N][256] f32

    char* wp = (char*)d_ws;
    auto alloc = [&](size_t bytes) {
        char* p = wp;
        wp += (bytes + 255) & ~(size_t)255;
        return p;
    };
    unsigned short* AGGS = (unsigned short*)alloc((size_t)RN * Dd * 2);   // 102.4 MB
    unsigned short* XB   = (unsigned short*)alloc((size_t)N * Dd * 2);    //  25.6 MB
    unsigned short* EMB  = (unsigned short*)alloc((size_t)N * Dd * 2);    //  25.6 MB
    unsigned short* BTm  = (unsigned short*)alloc((size_t)Dd * 1280 * 2); // 655 KB
    unsigned short* BTp  = (unsigned short*)alloc((size_t)Dd * Dd * 2);   // 131 KB
    float* WT  = (float*)alloc((size_t)R * Dd * 4);
    float* Y   = (float*)alloc((size_t)N * R * 4);
    float* SC  = (float*)alloc((size_t)N * R * 4);
    int* counts = (int*)alloc((size_t)RN * 4);
    int* offs   = (int*)alloc((size_t)RN * 4);
    int* cursor = (int*)alloc((size_t)RN * 4);
    int* bsums  = (int*)alloc(1024);
    u64* edata  = (u64*)alloc((size_t)RE * 8);                            // 25.6 MB

    const int gblocks = (N + 127) / 128;            // 391
    const int nblk    = (RN + 1023) / 1024;         // 196

    // 1. B-matrix prep + emb conversion (+x_all passthrough)
    build_bt<<<(1280 * 256 + 256 * 256 + 255) / 256, 256, 0, stream>>>(
        rel_W, self_W, pre_W, BTm, BTp);
    conv_emb<<<2048, 256, 0, stream>>>(node_emb, EMB, outX, N * Dd / 4);

    // 2. pre-encoder -> X bf16
    gemm_mfma<0><<<gblocks, 512, 0, stream>>>(EMB, nullptr, nullptr, nullptr, nullptr,
                                              BTp, pre_b, nullptr, ln1_g, ln1_b,
                                              nullptr, XB, N);
    // 3. w~ and y
    wtilde_kernel<<<R, 256, 0, stream>>>(rel_W, attn_vec, WT);
    y_kernel<<<(N + 3) / 4, 256, 0, stream>>>(XB, WT, Y, N);

    // 4. CSR build
    hipMemsetAsync(counts, 0, (size_t)RN * sizeof(int), stream);
    hist_rows<<<2048, 256, 0, stream>>>(rows, counts, RE, E, N);
    scan_blocks<<<nblk, 256, 0, stream>>>(counts, offs, bsums, RN);
    scan_bsums<<<1, 256, 0, stream>>>(bsums, nblk);
    scan_add<<<(RN + 255) / 256, 256, 0, stream>>>(offs, cursor, bsums, RN);
    scatter_edges<<<2048, 256, 0, stream>>>(rows, cols, vals, cursor, edata, RE, E, N);

    // 5. edge-wise scores -> masked softmax -> attn (outA)
    score_csr<<<(RN + 255) / 256, 256, 0, stream>>>(offs, edata, Y, SC, N, RE);
    softmax4<<<(N + 255) / 256, 256, 0, stream>>>(SC, outA, N);

    // 6. aggregation with fused attn scaling
    agg_csr<<<(RN + 3) / 4, 256, 0, stream>>>(offs, edata, XB, outA, AGGS, N, RE);

    // 7. mega-GEMM -> final (outF)
    gemm_mfma<1><<<gblocks, 512, 0, stream>>>(AGGS, AGGS + (size_t)N * Dd,
                                              AGGS + (size_t)2 * N * Dd,
                                              AGGS + (size_t)3 * N * Dd, XB,
                                              BTm, bias, self_b, ln2_g, ln2_b,
                                              outF, nullptr, N);
}